// Round 6
// baseline (480.839 us; speedup 1.0000x reference)
//
#include <hip/hip_runtime.h>
#include <hip/hip_bf16.h>

typedef __bf16 bf16;
typedef __attribute__((ext_vector_type(4))) __bf16 bf16x4;
typedef __attribute__((ext_vector_type(8))) __bf16 bf16x8;
typedef __attribute__((ext_vector_type(4))) float f32x4;
typedef __attribute__((ext_vector_type(16))) float f32x16;
typedef unsigned int u32;

#define D_MODEL 1024
#define NHEADS 16
#define DK 64
#define BATCH 2
#define SEQ 2048
#define NTOK (BATCH * SEQ)   // 4096

// 1/sqrt(64) * log2(e) folded into Q projection -> softmax runs in exp2 domain
#define QSCALE 0.18033688011112042f
#define DEFER_THR 8.0f       // defer O-rescale unless max grows by >8 (2^8 bound on P)

__device__ __forceinline__ u32 cvtpk_bf16(float lo, float hi) {
  u32 r;
  asm("v_cvt_pk_bf16_f32 %0, %1, %2" : "=v"(r) : "v"(lo), "v"(hi));
  return r;
}
__device__ __forceinline__ void plswap(u32& a, u32& b) {
  asm("v_permlane32_swap_b32 %0, %1" : "+v"(a), "+v"(b));
}
__device__ __forceinline__ float fast_exp2(float x) {
#if __has_builtin(__builtin_amdgcn_exp2f)
  return __builtin_amdgcn_exp2f(x);
#else
  return exp2f(x);
#endif
}
// Cross-half (lane ^ 32) combine — __shfl_xor (proven). Hand-rolled
// permlane32_swap in asm is a regalloc/hazard trap (R3/R4 post-mortems).
__device__ __forceinline__ float xhalf_max(float x) {
  return fmaxf(x, __shfl_xor(x, 32));
}
__device__ __forceinline__ float xhalf_add(float x) {
  return x + __shfl_xor(x, 32);
}

// ---------------------------------------------------------------------------
// fp32 -> bf16 conversions, batched launches
// ---------------------------------------------------------------------------
__global__ __launch_bounds__(256) void cvt3_kernel(
    const float* __restrict__ s0, const float* __restrict__ s1, const float* __restrict__ s2,
    bf16* __restrict__ d0, bf16* __restrict__ d1, bf16* __restrict__ d2, int n4) {
  int i = blockIdx.x * blockDim.x + threadIdx.x;
  if (i >= n4) return;
  const float* s = blockIdx.y == 0 ? s0 : blockIdx.y == 1 ? s1 : s2;
  bf16* d = blockIdx.y == 0 ? d0 : blockIdx.y == 1 ? d1 : d2;
  float4 v = reinterpret_cast<const float4*>(s)[i];
  bf16x4 o;
  o[0] = (bf16)v.x; o[1] = (bf16)v.y; o[2] = (bf16)v.z; o[3] = (bf16)v.w;
  reinterpret_cast<bf16x4*>(d)[i] = o;
}

__global__ __launch_bounds__(256) void cvt4_kernel(
    const float* __restrict__ s0, const float* __restrict__ s1,
    const float* __restrict__ s2, const float* __restrict__ s3,
    bf16* __restrict__ d0, bf16* __restrict__ d1, bf16* __restrict__ d2, bf16* __restrict__ d3,
    int n4) {
  int i = blockIdx.x * blockDim.x + threadIdx.x;
  if (i >= n4) return;
  const float* s = blockIdx.y == 0 ? s0 : blockIdx.y == 1 ? s1 : blockIdx.y == 2 ? s2 : s3;
  bf16* d = blockIdx.y == 0 ? d0 : blockIdx.y == 1 ? d1 : blockIdx.y == 2 ? d2 : d3;
  float4 v = reinterpret_cast<const float4*>(s)[i];
  bf16x4 o;
  o[0] = (bf16)v.x; o[1] = (bf16)v.y; o[2] = (bf16)v.z; o[3] = (bf16)v.w;
  reinterpret_cast<bf16x4*>(d)[i] = o;
}

// ---------------------------------------------------------------------------
// BT-GEMM core: 128x64 tile, BK=32, 4 waves in 2x2, each wave 64x32 (4x2 frags)
// ---------------------------------------------------------------------------
#define TM 128
#define TN 64
#define BK 32

#define ASYNC_COPY16(gptr, lptr)                                                \
  __builtin_amdgcn_global_load_lds(                                             \
      (__attribute__((address_space(1))) void*)(gptr),                          \
      (__attribute__((address_space(3))) void*)(lptr), 16, 0, 0)

__device__ __forceinline__ void gemm_core(
    const bf16* __restrict__ A, const bf16* __restrict__ Bw, int K,
    int m0, int n0, bf16 (*As)[BK], bf16 (*Bs)[BK], f32x4 (&acc)[4][2]) {
  const int t = threadIdx.x;
  const int wave = t >> 6;
  const int lane = t & 63;
  const int wr = (wave >> 1) * 64;
  const int wc = (wave & 1) * 32;
  const int r4 = lane >> 2;
  const int c8 = (lane & 3) * 8;
  const int fr = lane & 15;
  const int fk = (lane >> 4) * 8;

  for (int k0 = 0; k0 < K; k0 += BK) {
    ASYNC_COPY16(&A[(size_t)(m0 + wave * 16 + r4) * K + k0 + c8], &As[wave * 16][0]);
    ASYNC_COPY16(&A[(size_t)(m0 + 64 + wave * 16 + r4) * K + k0 + c8], &As[64 + wave * 16][0]);
    ASYNC_COPY16(&Bw[(size_t)(n0 + wave * 16 + r4) * K + k0 + c8], &Bs[wave * 16][0]);
    __syncthreads();

    bf16x8 af[4], bfr[2];
#pragma unroll
    for (int m = 0; m < 4; m++)
      af[m] = *reinterpret_cast<const bf16x8*>(&As[wr + m * 16 + fr][fk]);
#pragma unroll
    for (int n = 0; n < 2; n++)
      bfr[n] = *reinterpret_cast<const bf16x8*>(&Bs[wc + n * 16 + fr][fk]);
#pragma unroll
    for (int m = 0; m < 4; m++)
#pragma unroll
      for (int n = 0; n < 2; n++)
        acc[m][n] = __builtin_amdgcn_mfma_f32_16x16x32_bf16(af[m], bfr[n], acc[m][n], 0, 0, 0);
    __syncthreads();
  }
}

// Combined Q/K/V projection: grid.z selects which projection; z<2 -> [B,H,S,Dk]
// layout (Q gets QSCALE), z==2 -> V transposed [B,H,Dk,S].
struct ProjArgs {
  const bf16* A[3];
  const bf16* W[3];
  const float* bias[3];
  bf16* out[3];
};

__global__ __launch_bounds__(256) void gemm_proj(ProjArgs pa, int K) {
  __shared__ bf16 As[TM][BK];
  __shared__ bf16 Bs[TN][BK];
  const int z = blockIdx.z;
  const int m0 = blockIdx.x * TM;
  const int n0 = blockIdx.y * TN;
  f32x4 acc[4][2] = {};
  gemm_core(pa.A[z], pa.W[z], K, m0, n0, As, Bs, acc);

  const int lane = threadIdx.x & 63;
  const int wave = threadIdx.x >> 6;
  const int wr = (wave >> 1) * 64;
  const int wc = (wave & 1) * 32;
  const int fr = lane & 15;
  const float scale = (z == 0) ? QSCALE : 1.0f;
  const float* bias = pa.bias[z];
  bf16* out = pa.out[z];

#pragma unroll
  for (int m = 0; m < 4; m++) {
#pragma unroll
    for (int n = 0; n < 2; n++) {
      const int col = n0 + wc + n * 16 + fr;
      const float bv = bias[col];
#pragma unroll
      for (int j = 0; j < 4; j++) {
        const int row = m0 + wr + m * 16 + (lane >> 4) * 4 + j;
        const float v = (acc[m][n][j] + bv) * scale;
        const int b = row >> 11;
        const int s = row & (SEQ - 1);
        const int h = col >> 6;
        const int d = col & (DK - 1);
        if (z < 2)
          out[(((size_t)(b * NHEADS + h)) * SEQ + s) * DK + d] = (bf16)v;
        else
          out[(((size_t)(b * NHEADS + h)) * DK + d) * SEQ + s] = (bf16)v;
      }
    }
  }
}

__global__ __launch_bounds__(256) void gemm_out(
    const bf16* __restrict__ A, const bf16* __restrict__ Bw,
    const float* __restrict__ bias, float* __restrict__ out, int K) {
  __shared__ bf16 As[TM][BK];
  __shared__ bf16 Bs[TN][BK];
  const int m0 = blockIdx.x * TM;
  const int n0 = blockIdx.y * TN;
  f32x4 acc[4][2] = {};
  gemm_core(A, Bw, K, m0, n0, As, Bs, acc);

  const int lane = threadIdx.x & 63;
  const int wave = threadIdx.x >> 6;
  const int wr = (wave >> 1) * 64;
  const int wc = (wave & 1) * 32;
  const int fr = lane & 15;
#pragma unroll
  for (int m = 0; m < 4; m++) {
#pragma unroll
    for (int n = 0; n < 2; n++) {
      const int col = n0 + wc + n * 16 + fr;
      const float bv = bias[col];
#pragma unroll
      for (int j = 0; j < 4; j++) {
        const int row = m0 + wr + m * 16 + (lane >> 4) * 4 + j;
        out[(size_t)row * D_MODEL + col] = acc[m][n][j] + bv;
      }
    }
  }
}

// ---------------------------------------------------------------------------
// Flash attention, swapped-operand 32x32x16, split-KV across 2 waves/block.
// Both waves share one 32-row Q block; wave w handles interleaved KV tiles
// t = w, w+2, ... (16 each); partials merged once per block via LDS.
// Per wave: 2-deep pipeline (QK of next tile overlaps softmax of current),
// K prefetch distance 2, defer-rescale (T13), setprio (T5). No barriers in
// the tile loop.
// ---------------------------------------------------------------------------
#define QBLK 32
#define KVBLK 64
#define NT (SEQ / KVBLK)   // 32
#define NLOC (NT / 2)      // 16 tiles per wave

__global__ __launch_bounds__(128, 4) void attn_kernel(
    const bf16* __restrict__ Q,   // [B*H][SEQ][DK]  (pre-scaled)
    const bf16* __restrict__ Kb,  // [B*H][SEQ][DK]
    const bf16* __restrict__ Vt,  // [B*H][DK][SEQ]
    bf16* __restrict__ X) {       // [B][SEQ][D_MODEL]
  __shared__ float lds_o[32][64];   // wave1 partial O^T
  __shared__ float lds_ml[2][64];   // wave1 m, l

  const int lane = threadIdx.x & 63;
  const int wave = threadIdx.x >> 6;
  const int bh = blockIdx.y;
  const int bb = bh >> 4, hh = bh & (NHEADS - 1);
  const int q0 = blockIdx.x * QBLK;
  const int row = lane & 31, hi = lane >> 5;

  const bf16* Qp = Q + (size_t)bh * SEQ * DK;
  const bf16* Kp = Kb + (size_t)bh * SEQ * DK;
  const bf16* Vp = Vt + (size_t)bh * DK * SEQ;

  bf16x8 qf[4];
#pragma unroll
  for (int kd = 0; kd < 4; kd++)
    qf[kd] = *reinterpret_cast<const bf16x8*>(&Qp[(size_t)(q0 + row) * DK + kd * 16 + hi * 8]);

  f32x16 ot0, ot1;
#pragma unroll
  for (int r = 0; r < 16; r++) { ot0[r] = 0.f; ot1[r] = 0.f; }
  float m_run = -1e30f, l_run = 0.f;

  bf16x8 ka[2][4], kb2[2][4];

#define LOADK(dst, kv)                                                          \
  {                                                                             \
    _Pragma("unroll") for (int hf = 0; hf < 2; hf++)                            \
        _Pragma("unroll") for (int kd = 0; kd < 4; kd++)                        \
            dst[hf][kd] = *reinterpret_cast<const bf16x8*>(                     \
                &Kp[(size_t)((kv) + hf * 32 + row) * DK + kd * 16 + hi * 8]);   \
  }

  // local tile i (0..15) -> global tile index, wrapped
  auto gt = [&](int i) { return wave + 2 * (i & (NLOC - 1)); };

  // prologue: K for local 0,1 in flight; S[local 0] computed
  LOADK(ka, gt(0) * KVBLK)
  LOADK(kb2, gt(1) * KVBLK)
  f32x16 sa0, sa1, sb0, sb1;
#pragma unroll
  for (int r = 0; r < 16; r++) { sa0[r] = 0.f; sa1[r] = 0.f; }
  __builtin_amdgcn_s_setprio(1);
#pragma unroll
  for (int kd = 0; kd < 4; kd++)
    sa0 = __builtin_amdgcn_mfma_f32_32x32x16_bf16(ka[0][kd], qf[kd], sa0, 0, 0, 0);
#pragma unroll
  for (int kd = 0; kd < 4; kd++)
    sa1 = __builtin_amdgcn_mfma_f32_32x32x16_bf16(ka[1][kd], qf[kd], sa1, 0, 0, 0);
  __builtin_amdgcn_s_setprio(0);

  // pipelined body: softmax+PV of tile tc (scores in SC), QK of next local
  // tile (K-frags in KN -> scores SN), prefetch K[tp] into KL.
  auto pipe = [&](f32x16& SC0, f32x16& SC1, f32x16& SN0, f32x16& SN1,
                  bf16x8 (&KN)[2][4], bf16x8 (&KL)[2][4], int tc, int tp) {
    const int kv0 = tc * KVBLK;
#pragma unroll
    for (int r = 0; r < 16; r++) { SN0[r] = 0.f; SN1[r] = 0.f; }
    __builtin_amdgcn_s_setprio(1);
#pragma unroll
    for (int kd = 0; kd < 4; kd++)
      SN0 = __builtin_amdgcn_mfma_f32_32x32x16_bf16(KN[0][kd], qf[kd], SN0, 0, 0, 0);
#pragma unroll
    for (int kd = 0; kd < 4; kd++)
      SN1 = __builtin_amdgcn_mfma_f32_32x32x16_bf16(KN[1][kd], qf[kd], SN1, 0, 0, 0);
    __builtin_amdgcn_s_setprio(0);

    // prefetch K[tp] (wrapped at end; value unused past last tile)
    LOADK(KL, tp * KVBLK)

    // V fragments for tile tc (latency hidden under softmax)
    bf16x8 vf[2][4];
#pragma unroll
    for (int dh = 0; dh < 2; dh++)
#pragma unroll
      for (int ks = 0; ks < 4; ks++)
        vf[dh][ks] = *reinterpret_cast<const bf16x8*>(
            &Vp[(size_t)(dh * 32 + row) * SEQ + kv0 + ks * 16 + hi * 8]);

    // online softmax on SC (exp2 domain), defer-rescale (T13)
    float w16[16];
#pragma unroll
    for (int r = 0; r < 16; r++) w16[r] = fmaxf(SC0[r], SC1[r]);
#pragma unroll
    for (int r = 0; r < 8; r++) w16[r] = fmaxf(w16[r], w16[r + 8]);
#pragma unroll
    for (int r = 0; r < 4; r++) w16[r] = fmaxf(w16[r], w16[r + 4]);
    float mx = fmaxf(fmaxf(w16[0], w16[1]), fmaxf(w16[2], w16[3]));
    mx = xhalf_max(mx);
    if (__any(mx > m_run + DEFER_THR)) {
      const float mn = fmaxf(m_run, mx);
      const float alpha = fast_exp2(m_run - mn);
      m_run = mn;
      l_run *= alpha;
#pragma unroll
      for (int r = 0; r < 16; r++) { ot0[r] *= alpha; ot1[r] *= alpha; }
    }
    float p[32];
#pragma unroll
    for (int r = 0; r < 16; r++) p[r] = fast_exp2(SC0[r] - m_run);
#pragma unroll
    for (int r = 0; r < 16; r++) p[16 + r] = fast_exp2(SC1[r] - m_run);
    float a16[16];
#pragma unroll
    for (int r = 0; r < 16; r++) a16[r] = p[r] + p[r + 16];
#pragma unroll
    for (int r = 0; r < 8; r++) a16[r] += a16[r + 8];
#pragma unroll
    for (int r = 0; r < 4; r++) a16[r] += a16[r + 4];
    float rs = (a16[0] + a16[1]) + (a16[2] + a16[3]);
    l_run += xhalf_add(rs);

    // pack P -> P^T B-fragments (cvt_pk + permlane32_swap)
    u32 c[16];
#pragma unroll
    for (int i = 0; i < 8; i++) c[i] = cvtpk_bf16(p[2 * i], p[2 * i + 1]);
#pragma unroll
    for (int i = 0; i < 8; i++) c[8 + i] = cvtpk_bf16(p[16 + 2 * i], p[17 + 2 * i]);
    plswap(c[0], c[2]);   plswap(c[1], c[3]);
    plswap(c[4], c[6]);   plswap(c[5], c[7]);
    plswap(c[8], c[10]);  plswap(c[9], c[11]);
    plswap(c[12], c[14]); plswap(c[13], c[15]);
    bf16x8 pbv[4];
#pragma unroll
    for (int ks = 0; ks < 4; ks++) {
      union { u32 u[4]; bf16x8 v; } pk;
      pk.u[0] = c[ks * 4 + 0]; pk.u[1] = c[ks * 4 + 1];
      pk.u[2] = c[ks * 4 + 2]; pk.u[3] = c[ks * 4 + 3];
      pbv[ks] = pk.v;
    }

    // O^T += V^T . P^T
    __builtin_amdgcn_s_setprio(1);
#pragma unroll
    for (int ks = 0; ks < 4; ks++) {
      ot0 = __builtin_amdgcn_mfma_f32_32x32x16_bf16(vf[0][ks], pbv[ks], ot0, 0, 0, 0);
      ot1 = __builtin_amdgcn_mfma_f32_32x32x16_bf16(vf[1][ks], pbv[ks], ot1, 0, 0, 0);
    }
    __builtin_amdgcn_s_setprio(0);
  };

  for (int i = 0; i < NLOC; i += 2) {
    pipe(sa0, sa1, sb0, sb1, kb2, ka, gt(i), gt(i + 2));
    pipe(sb0, sb1, sa0, sa1, ka, kb2, gt(i + 1), gt(i + 3));
  }

  // ---- merge the two waves' partials (wave1 -> LDS, wave0 combines) ----
  if (wave == 1) {
#pragma unroll
    for (int r = 0; r < 16; r++) {
      lds_o[r][lane] = ot0[r];
      lds_o[16 + r][lane] = ot1[r];
    }
    lds_ml[0][lane] = m_run;
    lds_ml[1][lane] = l_run;
  }
  __syncthreads();
  if (wave == 0) {
    const float m1 = lds_ml[0][lane];
    const float l1 = lds_ml[1][lane];
    const float mm = fmaxf(m_run, m1);
    const float s0 = fast_exp2(m_run - mm);
    const float s1 = fast_exp2(m1 - mm);
    const float inv = 1.0f / (l_run * s0 + l1 * s1);
    bf16* Xp = X + ((size_t)bb * SEQ + q0 + row) * D_MODEL + hh * DK;
#pragma unroll
    for (int g = 0; g < 4; g++) {
      bf16x4 w0, w1;
#pragma unroll
      for (int j = 0; j < 4; j++) {
        w0[j] = (bf16)((ot0[g * 4 + j] * s0 + lds_o[g * 4 + j][lane] * s1) * inv);
        w1[j] = (bf16)((ot1[g * 4 + j] * s0 + lds_o[16 + g * 4 + j][lane] * s1) * inv);
      }
      *reinterpret_cast<bf16x4*>(&Xp[g * 8 + hi * 4]) = w0;
      *reinterpret_cast<bf16x4*>(&Xp[32 + g * 8 + hi * 4]) = w1;
    }
  }
}

// ---------------------------------------------------------------------------
extern "C" void kernel_launch(void* const* d_in, const int* in_sizes, int n_in,
                              void* d_out, int out_size, void* d_ws, size_t ws_size,
                              hipStream_t stream) {
  const float* q  = (const float*)d_in[0];
  const float* k  = (const float*)d_in[1];
  const float* v  = (const float*)d_in[2];
  const float* Wq = (const float*)d_in[3];
  const float* bq = (const float*)d_in[4];
  const float* Wk = (const float*)d_in[5];
  const float* bk = (const float*)d_in[6];
  const float* Wv = (const float*)d_in[7];
  const float* bv = (const float*)d_in[8];
  const float* Wo = (const float*)d_in[9];
  const float* bo = (const float*)d_in[10];

  char* ws = (char*)d_ws;
  size_t off = 0;
  auto alloc = [&](size_t bytes) -> void* {
    void* p = ws + off;
    off += (bytes + 255) & ~(size_t)255;
    return p;
  };
  const size_t ACT = (size_t)NTOK * D_MODEL;
  const size_t WEL = (size_t)D_MODEL * D_MODEL;

  bf16* Xq  = (bf16*)alloc(ACT * 2);
  bf16* Xk  = (bf16*)alloc(ACT * 2);
  bf16* Xv  = (bf16*)alloc(ACT * 2);
  bf16* Wqb = (bf16*)alloc(WEL * 2);
  bf16* Wkb = (bf16*)alloc(WEL * 2);
  bf16* Wvb = (bf16*)alloc(WEL * 2);
  bf16* Wob = (bf16*)alloc(WEL * 2);
  bf16* Qb  = (bf16*)alloc(ACT * 2);
  bf16* Kbf = (bf16*)alloc(ACT * 2);
  bf16* Vtb = (bf16*)alloc(ACT * 2);
  bf16* Xa  = (bf16*)alloc(ACT * 2);

  {
    int n4 = (int)(ACT / 4);
    cvt3_kernel<<<dim3((n4 + 255) / 256, 3), dim3(256), 0, stream>>>(q, k, v, Xq, Xk, Xv, n4);
  }
  {
    int n4 = (int)(WEL / 4);
    cvt4_kernel<<<dim3((n4 + 255) / 256, 4), dim3(256), 0, stream>>>(
        Wq, Wk, Wv, Wo, Wqb, Wkb, Wvb, Wob, n4);
  }

  ProjArgs pa;
  pa.A[0] = Xq;  pa.A[1] = Xk;  pa.A[2] = Xv;
  pa.W[0] = Wqb; pa.W[1] = Wkb; pa.W[2] = Wvb;
  pa.bias[0] = bq; pa.bias[1] = bk; pa.bias[2] = bv;
  pa.out[0] = Qb; pa.out[1] = Kbf; pa.out[2] = Vtb;
  gemm_proj<<<dim3(NTOK / TM, D_MODEL / TN, 3), dim3(256), 0, stream>>>(pa, D_MODEL);

  attn_kernel<<<dim3(SEQ / QBLK, BATCH * NHEADS), dim3(128), 0, stream>>>(Qb, Kbf, Vtb, Xa);

  gemm_out<<<dim3(NTOK / TM, D_MODEL / TN), dim3(256), 0, stream>>>(
      Xa, Wob, bo, (float*)d_out, D_MODEL);
}

// Round 7
// 230.957 us; speedup vs baseline: 2.0819x; 2.0819x over previous
//
#include <hip/hip_runtime.h>
#include <hip/hip_bf16.h>

typedef __bf16 bf16;
typedef __attribute__((ext_vector_type(4))) __bf16 bf16x4;
typedef __attribute__((ext_vector_type(8))) __bf16 bf16x8;
typedef __attribute__((ext_vector_type(4))) float f32x4;
typedef __attribute__((ext_vector_type(16))) float f32x16;
typedef unsigned int u32;

#define D_MODEL 1024
#define NHEADS 16
#define DK 64
#define BATCH 2
#define SEQ 2048
#define NTOK (BATCH * SEQ)   // 4096

// 1/sqrt(64) * log2(e) folded into Q projection -> softmax runs in exp2 domain
#define QSCALE 0.18033688011112042f
#define DEFER_THR 8.0f       // defer O-rescale unless max grows by >8 (2^8 bound on P)

__device__ __forceinline__ u32 cvtpk_bf16(float lo, float hi) {
  u32 r;
  asm("v_cvt_pk_bf16_f32 %0, %1, %2" : "=v"(r) : "v"(lo), "v"(hi));
  return r;
}
__device__ __forceinline__ void plswap(u32& a, u32& b) {
  asm("v_permlane32_swap_b32 %0, %1" : "+v"(a), "+v"(b));
}
__device__ __forceinline__ float fast_exp2(float x) {
#if __has_builtin(__builtin_amdgcn_exp2f)
  return __builtin_amdgcn_exp2f(x);
#else
  return exp2f(x);
#endif
}
// Cross-half (lane ^ 32) combine — __shfl_xor (proven). Hand-rolled
// permlane32_swap in asm is a regalloc/hazard trap (R3/R4 post-mortems).
__device__ __forceinline__ float xhalf_max(float x) {
  return fmaxf(x, __shfl_xor(x, 32));
}
__device__ __forceinline__ float xhalf_add(float x) {
  return x + __shfl_xor(x, 32);
}

// ---------------------------------------------------------------------------
// fp32 -> bf16 conversions, batched launches
// ---------------------------------------------------------------------------
__global__ __launch_bounds__(256) void cvt3_kernel(
    const float* __restrict__ s0, const float* __restrict__ s1, const float* __restrict__ s2,
    bf16* __restrict__ d0, bf16* __restrict__ d1, bf16* __restrict__ d2, int n4) {
  int i = blockIdx.x * blockDim.x + threadIdx.x;
  if (i >= n4) return;
  const float* s = blockIdx.y == 0 ? s0 : blockIdx.y == 1 ? s1 : s2;
  bf16* d = blockIdx.y == 0 ? d0 : blockIdx.y == 1 ? d1 : d2;
  float4 v = reinterpret_cast<const float4*>(s)[i];
  bf16x4 o;
  o[0] = (bf16)v.x; o[1] = (bf16)v.y; o[2] = (bf16)v.z; o[3] = (bf16)v.w;
  reinterpret_cast<bf16x4*>(d)[i] = o;
}

__global__ __launch_bounds__(256) void cvt4_kernel(
    const float* __restrict__ s0, const float* __restrict__ s1,
    const float* __restrict__ s2, const float* __restrict__ s3,
    bf16* __restrict__ d0, bf16* __restrict__ d1, bf16* __restrict__ d2, bf16* __restrict__ d3,
    int n4) {
  int i = blockIdx.x * blockDim.x + threadIdx.x;
  if (i >= n4) return;
  const float* s = blockIdx.y == 0 ? s0 : blockIdx.y == 1 ? s1 : blockIdx.y == 2 ? s2 : s3;
  bf16* d = blockIdx.y == 0 ? d0 : blockIdx.y == 1 ? d1 : blockIdx.y == 2 ? d2 : d3;
  float4 v = reinterpret_cast<const float4*>(s)[i];
  bf16x4 o;
  o[0] = (bf16)v.x; o[1] = (bf16)v.y; o[2] = (bf16)v.z; o[3] = (bf16)v.w;
  reinterpret_cast<bf16x4*>(d)[i] = o;
}

// ---------------------------------------------------------------------------
// BT-GEMM core: 128x64 tile, BK=32, 4 waves in 2x2, each wave 64x32 (4x2 frags)
// ---------------------------------------------------------------------------
#define TM 128
#define TN 64
#define BK 32

#define ASYNC_COPY16(gptr, lptr)                                                \
  __builtin_amdgcn_global_load_lds(                                             \
      (__attribute__((address_space(1))) void*)(gptr),                          \
      (__attribute__((address_space(3))) void*)(lptr), 16, 0, 0)

__device__ __forceinline__ void gemm_core(
    const bf16* __restrict__ A, const bf16* __restrict__ Bw, int K,
    int m0, int n0, bf16 (*As)[BK], bf16 (*Bs)[BK], f32x4 (&acc)[4][2]) {
  const int t = threadIdx.x;
  const int wave = t >> 6;
  const int lane = t & 63;
  const int wr = (wave >> 1) * 64;
  const int wc = (wave & 1) * 32;
  const int r4 = lane >> 2;
  const int c8 = (lane & 3) * 8;
  const int fr = lane & 15;
  const int fk = (lane >> 4) * 8;

  for (int k0 = 0; k0 < K; k0 += BK) {
    ASYNC_COPY16(&A[(size_t)(m0 + wave * 16 + r4) * K + k0 + c8], &As[wave * 16][0]);
    ASYNC_COPY16(&A[(size_t)(m0 + 64 + wave * 16 + r4) * K + k0 + c8], &As[64 + wave * 16][0]);
    ASYNC_COPY16(&Bw[(size_t)(n0 + wave * 16 + r4) * K + k0 + c8], &Bs[wave * 16][0]);
    __syncthreads();

    bf16x8 af[4], bfr[2];
#pragma unroll
    for (int m = 0; m < 4; m++)
      af[m] = *reinterpret_cast<const bf16x8*>(&As[wr + m * 16 + fr][fk]);
#pragma unroll
    for (int n = 0; n < 2; n++)
      bfr[n] = *reinterpret_cast<const bf16x8*>(&Bs[wc + n * 16 + fr][fk]);
#pragma unroll
    for (int m = 0; m < 4; m++)
#pragma unroll
      for (int n = 0; n < 2; n++)
        acc[m][n] = __builtin_amdgcn_mfma_f32_16x16x32_bf16(af[m], bfr[n], acc[m][n], 0, 0, 0);
    __syncthreads();
  }
}

// Combined Q/K/V projection: grid.z selects which projection; z<2 -> [B,H,S,Dk]
// layout (Q gets QSCALE), z==2 -> V transposed [B,H,Dk,S].
struct ProjArgs {
  const bf16* A[3];
  const bf16* W[3];
  const float* bias[3];
  bf16* out[3];
};

__global__ __launch_bounds__(256) void gemm_proj(ProjArgs pa, int K) {
  __shared__ bf16 As[TM][BK];
  __shared__ bf16 Bs[TN][BK];
  const int z = blockIdx.z;
  const int m0 = blockIdx.x * TM;
  const int n0 = blockIdx.y * TN;
  f32x4 acc[4][2] = {};
  gemm_core(pa.A[z], pa.W[z], K, m0, n0, As, Bs, acc);

  const int lane = threadIdx.x & 63;
  const int wave = threadIdx.x >> 6;
  const int wr = (wave >> 1) * 64;
  const int wc = (wave & 1) * 32;
  const int fr = lane & 15;
  const float scale = (z == 0) ? QSCALE : 1.0f;
  const float* bias = pa.bias[z];
  bf16* out = pa.out[z];

#pragma unroll
  for (int m = 0; m < 4; m++) {
#pragma unroll
    for (int n = 0; n < 2; n++) {
      const int col = n0 + wc + n * 16 + fr;
      const float bv = bias[col];
#pragma unroll
      for (int j = 0; j < 4; j++) {
        const int row = m0 + wr + m * 16 + (lane >> 4) * 4 + j;
        const float v = (acc[m][n][j] + bv) * scale;
        const int b = row >> 11;
        const int s = row & (SEQ - 1);
        const int h = col >> 6;
        const int d = col & (DK - 1);
        if (z < 2)
          out[(((size_t)(b * NHEADS + h)) * SEQ + s) * DK + d] = (bf16)v;
        else
          out[(((size_t)(b * NHEADS + h)) * DK + d) * SEQ + s] = (bf16)v;
      }
    }
  }
}

__global__ __launch_bounds__(256) void gemm_out(
    const bf16* __restrict__ A, const bf16* __restrict__ Bw,
    const float* __restrict__ bias, float* __restrict__ out, int K) {
  __shared__ bf16 As[TM][BK];
  __shared__ bf16 Bs[TN][BK];
  const int m0 = blockIdx.x * TM;
  const int n0 = blockIdx.y * TN;
  f32x4 acc[4][2] = {};
  gemm_core(A, Bw, K, m0, n0, As, Bs, acc);

  const int lane = threadIdx.x & 63;
  const int wave = threadIdx.x >> 6;
  const int wr = (wave >> 1) * 64;
  const int wc = (wave & 1) * 32;
  const int fr = lane & 15;
#pragma unroll
  for (int m = 0; m < 4; m++) {
#pragma unroll
    for (int n = 0; n < 2; n++) {
      const int col = n0 + wc + n * 16 + fr;
      const float bv = bias[col];
#pragma unroll
      for (int j = 0; j < 4; j++) {
        const int row = m0 + wr + m * 16 + (lane >> 4) * 4 + j;
        out[(size_t)row * D_MODEL + col] = acc[m][n][j] + bv;
      }
    }
  }
}

// ---------------------------------------------------------------------------
// Flash attention, swapped-operand 32x32x16, split-KV across 2 waves/block.
// Both waves share one 32-row Q block; wave w handles interleaved KV tiles
// t = w, w+2, ... (16 each); partials merged once per block via LDS.
// __launch_bounds__(128, 2): VGPR cap 256 — R6's (128,4) capped VGPR at 64
// and spilled the whole S/O/K state to scratch (1.7 GB HBM traffic/dispatch).
// ---------------------------------------------------------------------------
#define QBLK 32
#define KVBLK 64
#define NT (SEQ / KVBLK)   // 32
#define NLOC (NT / 2)      // 16 tiles per wave

__global__ __launch_bounds__(128, 2) void attn_kernel(
    const bf16* __restrict__ Q,   // [B*H][SEQ][DK]  (pre-scaled)
    const bf16* __restrict__ Kb,  // [B*H][SEQ][DK]
    const bf16* __restrict__ Vt,  // [B*H][DK][SEQ]
    bf16* __restrict__ X) {       // [B][SEQ][D_MODEL]
  __shared__ float lds_o[32][64];   // wave1 partial O^T
  __shared__ float lds_ml[2][64];   // wave1 m, l

  const int lane = threadIdx.x & 63;
  const int wave = threadIdx.x >> 6;
  const int bh = blockIdx.y;
  const int bb = bh >> 4, hh = bh & (NHEADS - 1);
  const int q0 = blockIdx.x * QBLK;
  const int row = lane & 31, hi = lane >> 5;

  const bf16* Qp = Q + (size_t)bh * SEQ * DK;
  const bf16* Kp = Kb + (size_t)bh * SEQ * DK;
  const bf16* Vp = Vt + (size_t)bh * DK * SEQ;

  bf16x8 qf[4];
#pragma unroll
  for (int kd = 0; kd < 4; kd++)
    qf[kd] = *reinterpret_cast<const bf16x8*>(&Qp[(size_t)(q0 + row) * DK + kd * 16 + hi * 8]);

  f32x16 ot0, ot1;
#pragma unroll
  for (int r = 0; r < 16; r++) { ot0[r] = 0.f; ot1[r] = 0.f; }
  float m_run = -1e30f, l_run = 0.f;

  bf16x8 ka[2][4], kb2[2][4];

#define LOADK(dst, kv)                                                          \
  {                                                                             \
    _Pragma("unroll") for (int hf = 0; hf < 2; hf++)                            \
        _Pragma("unroll") for (int kd = 0; kd < 4; kd++)                        \
            dst[hf][kd] = *reinterpret_cast<const bf16x8*>(                     \
                &Kp[(size_t)((kv) + hf * 32 + row) * DK + kd * 16 + hi * 8]);   \
  }

  // local tile i (0..15) -> global tile index, wrapped
  auto gt = [&](int i) { return wave + 2 * (i & (NLOC - 1)); };

  // prologue: K for local 0,1 in flight; S[local 0] computed
  LOADK(ka, gt(0) * KVBLK)
  LOADK(kb2, gt(1) * KVBLK)
  f32x16 sa0, sa1, sb0, sb1;
#pragma unroll
  for (int r = 0; r < 16; r++) { sa0[r] = 0.f; sa1[r] = 0.f; }
  __builtin_amdgcn_s_setprio(1);
#pragma unroll
  for (int kd = 0; kd < 4; kd++)
    sa0 = __builtin_amdgcn_mfma_f32_32x32x16_bf16(ka[0][kd], qf[kd], sa0, 0, 0, 0);
#pragma unroll
  for (int kd = 0; kd < 4; kd++)
    sa1 = __builtin_amdgcn_mfma_f32_32x32x16_bf16(ka[1][kd], qf[kd], sa1, 0, 0, 0);
  __builtin_amdgcn_s_setprio(0);

  // pipelined body: softmax+PV of tile tc (scores in SC), QK of next local
  // tile (K-frags in KN -> scores SN), prefetch K[tp] into KL.
  auto pipe = [&](f32x16& SC0, f32x16& SC1, f32x16& SN0, f32x16& SN1,
                  bf16x8 (&KN)[2][4], bf16x8 (&KL)[2][4], int tc, int tp) {
    const int kv0 = tc * KVBLK;
#pragma unroll
    for (int r = 0; r < 16; r++) { SN0[r] = 0.f; SN1[r] = 0.f; }
    __builtin_amdgcn_s_setprio(1);
#pragma unroll
    for (int kd = 0; kd < 4; kd++)
      SN0 = __builtin_amdgcn_mfma_f32_32x32x16_bf16(KN[0][kd], qf[kd], SN0, 0, 0, 0);
#pragma unroll
    for (int kd = 0; kd < 4; kd++)
      SN1 = __builtin_amdgcn_mfma_f32_32x32x16_bf16(KN[1][kd], qf[kd], SN1, 0, 0, 0);
    __builtin_amdgcn_s_setprio(0);

    // prefetch K[tp] (wrapped at end; value unused past last tile)
    LOADK(KL, tp * KVBLK)

    // V fragments for tile tc (latency hidden under softmax)
    bf16x8 vf[2][4];
#pragma unroll
    for (int dh = 0; dh < 2; dh++)
#pragma unroll
      for (int ks = 0; ks < 4; ks++)
        vf[dh][ks] = *reinterpret_cast<const bf16x8*>(
            &Vp[(size_t)(dh * 32 + row) * SEQ + kv0 + ks * 16 + hi * 8]);

    // online softmax on SC (exp2 domain), defer-rescale (T13)
    float w16[16];
#pragma unroll
    for (int r = 0; r < 16; r++) w16[r] = fmaxf(SC0[r], SC1[r]);
#pragma unroll
    for (int r = 0; r < 8; r++) w16[r] = fmaxf(w16[r], w16[r + 8]);
#pragma unroll
    for (int r = 0; r < 4; r++) w16[r] = fmaxf(w16[r], w16[r + 4]);
    float mx = fmaxf(fmaxf(w16[0], w16[1]), fmaxf(w16[2], w16[3]));
    mx = xhalf_max(mx);
    if (__any(mx > m_run + DEFER_THR)) {
      const float mn = fmaxf(m_run, mx);
      const float alpha = fast_exp2(m_run - mn);
      m_run = mn;
      l_run *= alpha;
#pragma unroll
      for (int r = 0; r < 16; r++) { ot0[r] *= alpha; ot1[r] *= alpha; }
    }
    float p[32];
#pragma unroll
    for (int r = 0; r < 16; r++) p[r] = fast_exp2(SC0[r] - m_run);
#pragma unroll
    for (int r = 0; r < 16; r++) p[16 + r] = fast_exp2(SC1[r] - m_run);
    float a16[16];
#pragma unroll
    for (int r = 0; r < 16; r++) a16[r] = p[r] + p[r + 16];
#pragma unroll
    for (int r = 0; r < 8; r++) a16[r] += a16[r + 8];
#pragma unroll
    for (int r = 0; r < 4; r++) a16[r] += a16[r + 4];
    float rs = (a16[0] + a16[1]) + (a16[2] + a16[3]);
    l_run += xhalf_add(rs);

    // pack P -> P^T B-fragments (cvt_pk + permlane32_swap)
    u32 c[16];
#pragma unroll
    for (int i = 0; i < 8; i++) c[i] = cvtpk_bf16(p[2 * i], p[2 * i + 1]);
#pragma unroll
    for (int i = 0; i < 8; i++) c[8 + i] = cvtpk_bf16(p[16 + 2 * i], p[17 + 2 * i]);
    plswap(c[0], c[2]);   plswap(c[1], c[3]);
    plswap(c[4], c[6]);   plswap(c[5], c[7]);
    plswap(c[8], c[10]);  plswap(c[9], c[11]);
    plswap(c[12], c[14]); plswap(c[13], c[15]);
    bf16x8 pbv[4];
#pragma unroll
    for (int ks = 0; ks < 4; ks++) {
      union { u32 u[4]; bf16x8 v; } pk;
      pk.u[0] = c[ks * 4 + 0]; pk.u[1] = c[ks * 4 + 1];
      pk.u[2] = c[ks * 4 + 2]; pk.u[3] = c[ks * 4 + 3];
      pbv[ks] = pk.v;
    }

    // O^T += V^T . P^T
    __builtin_amdgcn_s_setprio(1);
#pragma unroll
    for (int ks = 0; ks < 4; ks++) {
      ot0 = __builtin_amdgcn_mfma_f32_32x32x16_bf16(vf[0][ks], pbv[ks], ot0, 0, 0, 0);
      ot1 = __builtin_amdgcn_mfma_f32_32x32x16_bf16(vf[1][ks], pbv[ks], ot1, 0, 0, 0);
    }
    __builtin_amdgcn_s_setprio(0);
  };

  for (int i = 0; i < NLOC; i += 2) {
    pipe(sa0, sa1, sb0, sb1, kb2, ka, gt(i), gt(i + 2));
    pipe(sb0, sb1, sa0, sa1, ka, kb2, gt(i + 1), gt(i + 3));
  }

  // ---- merge the two waves' partials (wave1 -> LDS, wave0 combines) ----
  if (wave == 1) {
#pragma unroll
    for (int r = 0; r < 16; r++) {
      lds_o[r][lane] = ot0[r];
      lds_o[16 + r][lane] = ot1[r];
    }
    lds_ml[0][lane] = m_run;
    lds_ml[1][lane] = l_run;
  }
  __syncthreads();
  if (wave == 0) {
    const float m1 = lds_ml[0][lane];
    const float l1 = lds_ml[1][lane];
    const float mm = fmaxf(m_run, m1);
    const float s0 = fast_exp2(m_run - mm);
    const float s1 = fast_exp2(m1 - mm);
    const float inv = 1.0f / (l_run * s0 + l1 * s1);
    bf16* Xp = X + ((size_t)bb * SEQ + q0 + row) * D_MODEL + hh * DK;
#pragma unroll
    for (int g = 0; g < 4; g++) {
      bf16x4 w0, w1;
#pragma unroll
      for (int j = 0; j < 4; j++) {
        w0[j] = (bf16)((ot0[g * 4 + j] * s0 + lds_o[g * 4 + j][lane] * s1) * inv);
        w1[j] = (bf16)((ot1[g * 4 + j] * s0 + lds_o[16 + g * 4 + j][lane] * s1) * inv);
      }
      *reinterpret_cast<bf16x4*>(&Xp[g * 8 + hi * 4]) = w0;
      *reinterpret_cast<bf16x4*>(&Xp[32 + g * 8 + hi * 4]) = w1;
    }
  }
}

// ---------------------------------------------------------------------------
extern "C" void kernel_launch(void* const* d_in, const int* in_sizes, int n_in,
                              void* d_out, int out_size, void* d_ws, size_t ws_size,
                              hipStream_t stream) {
  const float* q  = (const float*)d_in[0];
  const float* k  = (const float*)d_in[1];
  const float* v  = (const float*)d_in[2];
  const float* Wq = (const float*)d_in[3];
  const float* bq = (const float*)d_in[4];
  const float* Wk = (const float*)d_in[5];
  const float* bk = (const float*)d_in[6];
  const float* Wv = (const float*)d_in[7];
  const float* bv = (const float*)d_in[8];
  const float* Wo = (const float*)d_in[9];
  const float* bo = (const float*)d_in[10];

  char* ws = (char*)d_ws;
  size_t off = 0;
  auto alloc = [&](size_t bytes) -> void* {
    void* p = ws + off;
    off += (bytes + 255) & ~(size_t)255;
    return p;
  };
  const size_t ACT = (size_t)NTOK * D_MODEL;
  const size_t WEL = (size_t)D_MODEL * D_MODEL;

  bf16* Xq  = (bf16*)alloc(ACT * 2);
  bf16* Xk  = (bf16*)alloc(ACT * 2);
  bf16* Xv  = (bf16*)alloc(ACT * 2);
  bf16* Wqb = (bf16*)alloc(WEL * 2);
  bf16* Wkb = (bf16*)alloc(WEL * 2);
  bf16* Wvb = (bf16*)alloc(WEL * 2);
  bf16* Wob = (bf16*)alloc(WEL * 2);
  bf16* Qb  = (bf16*)alloc(ACT * 2);
  bf16* Kbf = (bf16*)alloc(ACT * 2);
  bf16* Vtb = (bf16*)alloc(ACT * 2);
  bf16* Xa  = (bf16*)alloc(ACT * 2);

  {
    int n4 = (int)(ACT / 4);
    cvt3_kernel<<<dim3((n4 + 255) / 256, 3), dim3(256), 0, stream>>>(q, k, v, Xq, Xk, Xv, n4);
  }
  {
    int n4 = (int)(WEL / 4);
    cvt4_kernel<<<dim3((n4 + 255) / 256, 4), dim3(256), 0, stream>>>(
        Wq, Wk, Wv, Wo, Wqb, Wkb, Wvb, Wob, n4);
  }

  ProjArgs pa;
  pa.A[0] = Xq;  pa.A[1] = Xk;  pa.A[2] = Xv;
  pa.W[0] = Wqb; pa.W[1] = Wkb; pa.W[2] = Wvb;
  pa.bias[0] = bq; pa.bias[1] = bk; pa.bias[2] = bv;
  pa.out[0] = Qb; pa.out[1] = Kbf; pa.out[2] = Vtb;
  gemm_proj<<<dim3(NTOK / TM, D_MODEL / TN, 3), dim3(256), 0, stream>>>(pa, D_MODEL);

  attn_kernel<<<dim3(SEQ / QBLK, BATCH * NHEADS), dim3(128), 0, stream>>>(Qb, Kbf, Vtb, Xa);

  gemm_out<<<dim3(NTOK / TM, D_MODEL / TN), dim3(256), 0, stream>>>(
      Xa, Wob, bo, (float*)d_out, D_MODEL);
}

// Round 8
// 149.048 us; speedup vs baseline: 3.2261x; 1.5496x over previous
//
#include <hip/hip_runtime.h>
#include <hip/hip_bf16.h>

typedef __bf16 bf16;
typedef __attribute__((ext_vector_type(4))) __bf16 bf16x4;
typedef __attribute__((ext_vector_type(8))) __bf16 bf16x8;
typedef __attribute__((ext_vector_type(4))) float f32x4;
typedef __attribute__((ext_vector_type(16))) float f32x16;
typedef unsigned int u32;

#define D_MODEL 1024
#define NHEADS 16
#define DK 64
#define BATCH 2
#define SEQ 2048
#define NTOK (BATCH * SEQ)   // 4096

// 1/sqrt(64) * log2(e) folded into Q projection -> softmax runs in exp2 domain
#define QSCALE 0.18033688011112042f
#define DEFER_THR 8.0f       // defer O-rescale unless max grows by >8 (2^8 bound on P)

__device__ __forceinline__ u32 cvtpk_bf16(float lo, float hi) {
  u32 r;
  asm("v_cvt_pk_bf16_f32 %0, %1, %2" : "=v"(r) : "v"(lo), "v"(hi));
  return r;
}
__device__ __forceinline__ void plswap(u32& a, u32& b) {
  asm("v_permlane32_swap_b32 %0, %1" : "+v"(a), "+v"(b));
}
__device__ __forceinline__ float fast_exp2(float x) {
#if __has_builtin(__builtin_amdgcn_exp2f)
  return __builtin_amdgcn_exp2f(x);
#else
  return exp2f(x);
#endif
}
// Cross-half (lane ^ 32) combine — __shfl_xor (proven; hand-rolled permlane
// asm was a regalloc/hazard trap, R3/R4 post-mortems).
__device__ __forceinline__ float xhalf_max(float x) {
  return fmaxf(x, __shfl_xor(x, 32));
}
__device__ __forceinline__ float xhalf_add(float x) {
  return x + __shfl_xor(x, 32);
}

// ---------------------------------------------------------------------------
// Fragment-packed layouts (per head, SEQ*DK elems each). Lane l = hi*32+row.
//   Qf: [s/32][kd 0..3][lane][8]     lane supplies B-frag col=s&31, k=kd*16+hi*8+j
//   Kf: [s/64][hf*4+kd][lane][8]     A-frag row=s&31 (hf half), k=kd*16+hi*8+j
//   Vf: [s/64][dh*4+ks][lane][8]     A-frag row d=dh*32+(d&31), kv=ks*16+hi*8+j
// Every attn load = base + lane*16B + const  ->  one coalesced 1KB transaction.
// ---------------------------------------------------------------------------
__device__ __forceinline__ int frag_off_q(int s, int d) {
  return ((s >> 5) << 11) + ((d >> 4) << 9) + ((((d >> 3) & 1) * 32 + (s & 31)) << 3) + (d & 7);
}
__device__ __forceinline__ int frag_off_k(int s, int d) {
  return ((s >> 6) << 12) + ((((s >> 5) & 1) * 4 + (d >> 4)) << 9) +
         ((((d >> 3) & 1) * 32 + (s & 31)) << 3) + (d & 7);
}
__device__ __forceinline__ int frag_off_v(int s, int d) {
  return ((s >> 6) << 12) + (((d >> 5) * 4 + ((s >> 4) & 3)) << 9) +
         ((((s >> 3) & 1) * 32 + (d & 31)) << 3) + (s & 7);
}

// ---------------------------------------------------------------------------
// fp32 -> bf16 conversions, batched launches
// ---------------------------------------------------------------------------
__global__ __launch_bounds__(256) void cvt3_kernel(
    const float* __restrict__ s0, const float* __restrict__ s1, const float* __restrict__ s2,
    bf16* __restrict__ d0, bf16* __restrict__ d1, bf16* __restrict__ d2, int n4) {
  int i = blockIdx.x * blockDim.x + threadIdx.x;
  if (i >= n4) return;
  const float* s = blockIdx.y == 0 ? s0 : blockIdx.y == 1 ? s1 : s2;
  bf16* d = blockIdx.y == 0 ? d0 : blockIdx.y == 1 ? d1 : d2;
  float4 v = reinterpret_cast<const float4*>(s)[i];
  bf16x4 o;
  o[0] = (bf16)v.x; o[1] = (bf16)v.y; o[2] = (bf16)v.z; o[3] = (bf16)v.w;
  reinterpret_cast<bf16x4*>(d)[i] = o;
}

__global__ __launch_bounds__(256) void cvt4_kernel(
    const float* __restrict__ s0, const float* __restrict__ s1,
    const float* __restrict__ s2, const float* __restrict__ s3,
    bf16* __restrict__ d0, bf16* __restrict__ d1, bf16* __restrict__ d2, bf16* __restrict__ d3,
    int n4) {
  int i = blockIdx.x * blockDim.x + threadIdx.x;
  if (i >= n4) return;
  const float* s = blockIdx.y == 0 ? s0 : blockIdx.y == 1 ? s1 : blockIdx.y == 2 ? s2 : s3;
  bf16* d = blockIdx.y == 0 ? d0 : blockIdx.y == 1 ? d1 : blockIdx.y == 2 ? d2 : d3;
  float4 v = reinterpret_cast<const float4*>(s)[i];
  bf16x4 o;
  o[0] = (bf16)v.x; o[1] = (bf16)v.y; o[2] = (bf16)v.z; o[3] = (bf16)v.w;
  reinterpret_cast<bf16x4*>(d)[i] = o;
}

// ---------------------------------------------------------------------------
// BT-GEMM core: 128x64 tile, BK=32, 4 waves in 2x2, each wave 64x32 (4x2 frags)
// ---------------------------------------------------------------------------
#define TM 128
#define TN 64
#define BK 32

#define ASYNC_COPY16(gptr, lptr)                                                \
  __builtin_amdgcn_global_load_lds(                                             \
      (__attribute__((address_space(1))) void*)(gptr),                          \
      (__attribute__((address_space(3))) void*)(lptr), 16, 0, 0)

__device__ __forceinline__ void gemm_core(
    const bf16* __restrict__ A, const bf16* __restrict__ Bw, int K,
    int m0, int n0, bf16 (*As)[BK], bf16 (*Bs)[BK], f32x4 (&acc)[4][2]) {
  const int t = threadIdx.x;
  const int wave = t >> 6;
  const int lane = t & 63;
  const int wr = (wave >> 1) * 64;
  const int wc = (wave & 1) * 32;
  const int r4 = lane >> 2;
  const int c8 = (lane & 3) * 8;
  const int fr = lane & 15;
  const int fk = (lane >> 4) * 8;

  for (int k0 = 0; k0 < K; k0 += BK) {
    ASYNC_COPY16(&A[(size_t)(m0 + wave * 16 + r4) * K + k0 + c8], &As[wave * 16][0]);
    ASYNC_COPY16(&A[(size_t)(m0 + 64 + wave * 16 + r4) * K + k0 + c8], &As[64 + wave * 16][0]);
    ASYNC_COPY16(&Bw[(size_t)(n0 + wave * 16 + r4) * K + k0 + c8], &Bs[wave * 16][0]);
    __syncthreads();

    bf16x8 af[4], bfr[2];
#pragma unroll
    for (int m = 0; m < 4; m++)
      af[m] = *reinterpret_cast<const bf16x8*>(&As[wr + m * 16 + fr][fk]);
#pragma unroll
    for (int n = 0; n < 2; n++)
      bfr[n] = *reinterpret_cast<const bf16x8*>(&Bs[wc + n * 16 + fr][fk]);
#pragma unroll
    for (int m = 0; m < 4; m++)
#pragma unroll
      for (int n = 0; n < 2; n++)
        acc[m][n] = __builtin_amdgcn_mfma_f32_16x16x32_bf16(af[m], bfr[n], acc[m][n], 0, 0, 0);
    __syncthreads();
  }
}

// Combined Q/K/V projection: grid.z selects projection; epilogue writes the
// fragment-packed layout for the attention kernel (see frag_off_*).
struct ProjArgs {
  const bf16* A[3];
  const bf16* W[3];
  const float* bias[3];
  bf16* out[3];
};

__global__ __launch_bounds__(256) void gemm_proj(ProjArgs pa, int K) {
  __shared__ bf16 As[TM][BK];
  __shared__ bf16 Bs[TN][BK];
  const int z = blockIdx.z;
  const int m0 = blockIdx.x * TM;
  const int n0 = blockIdx.y * TN;
  f32x4 acc[4][2] = {};
  gemm_core(pa.A[z], pa.W[z], K, m0, n0, As, Bs, acc);

  const int lane = threadIdx.x & 63;
  const int wave = threadIdx.x >> 6;
  const int wr = (wave >> 1) * 64;
  const int wc = (wave & 1) * 32;
  const int fr = lane & 15;
  const float scale = (z == 0) ? QSCALE : 1.0f;
  const float* bias = pa.bias[z];
  bf16* out = pa.out[z];

#pragma unroll
  for (int m = 0; m < 4; m++) {
#pragma unroll
    for (int n = 0; n < 2; n++) {
      const int col = n0 + wc + n * 16 + fr;
      const float bv = bias[col];
#pragma unroll
      for (int j = 0; j < 4; j++) {
        const int row = m0 + wr + m * 16 + (lane >> 4) * 4 + j;
        const float v = (acc[m][n][j] + bv) * scale;
        const int b = row >> 11;
        const int s = row & (SEQ - 1);
        const int h = col >> 6;
        const int d = col & (DK - 1);
        const size_t base = (size_t)(b * NHEADS + h) * SEQ * DK;
        int off;
        if (z == 0)      off = frag_off_q(s, d);
        else if (z == 1) off = frag_off_k(s, d);
        else             off = frag_off_v(s, d);
        out[base + off] = (bf16)v;
      }
    }
  }
}

__global__ __launch_bounds__(256) void gemm_out(
    const bf16* __restrict__ A, const bf16* __restrict__ Bw,
    const float* __restrict__ bias, float* __restrict__ out, int K) {
  __shared__ bf16 As[TM][BK];
  __shared__ bf16 Bs[TN][BK];
  const int m0 = blockIdx.x * TM;
  const int n0 = blockIdx.y * TN;
  f32x4 acc[4][2] = {};
  gemm_core(A, Bw, K, m0, n0, As, Bs, acc);

  const int lane = threadIdx.x & 63;
  const int wave = threadIdx.x >> 6;
  const int wr = (wave >> 1) * 64;
  const int wc = (wave & 1) * 32;
  const int fr = lane & 15;
#pragma unroll
  for (int m = 0; m < 4; m++) {
#pragma unroll
    for (int n = 0; n < 2; n++) {
      const int col = n0 + wc + n * 16 + fr;
      const float bv = bias[col];
#pragma unroll
      for (int j = 0; j < 4; j++) {
        const int row = m0 + wr + m * 16 + (lane >> 4) * 4 + j;
        out[(size_t)row * D_MODEL + col] = acc[m][n][j] + bv;
      }
    }
  }
}

// ---------------------------------------------------------------------------
// Flash attention, swapped-operand 32x32x16, fragment-packed global loads.
// 4 waves/block; wave w owns q-rows blockIdx.x*128 + w*32 .. +31 and iterates
// ALL KV tiles (R5-proven body: 2-deep QK||softmax pipeline, K prefetch
// distance 2, defer-rescale, setprio). No LDS, no barriers, no merge.
// Every K/V/Q load: base + lane*16B + const imm  (1KB coalesced / instr).
// ---------------------------------------------------------------------------
#define QBLK 32
#define KVBLK 64
#define NT (SEQ / KVBLK)   // 32

__global__ __launch_bounds__(256, 2) void attn_kernel(
    const bf16* __restrict__ Qf,  // packed (frag_off_q), pre-scaled
    const bf16* __restrict__ Kf,  // packed (frag_off_k)
    const bf16* __restrict__ Vf,  // packed (frag_off_v)
    bf16* __restrict__ X) {       // [B][SEQ][D_MODEL]
  const int lane = threadIdx.x & 63;
  const int wave = threadIdx.x >> 6;
  const int bh = blockIdx.y;
  const int bb = bh >> 4, hh = bh & (NHEADS - 1);
  const int q0 = blockIdx.x * (QBLK * 4) + wave * QBLK;
  const int row = lane & 31, hi = lane >> 5;

  const bf16* Qp = Qf + (size_t)bh * SEQ * DK + (size_t)q0 * DK;  // q0*DK == (q0/32)*2048
  const bf16* Kp = Kf + (size_t)bh * SEQ * DK;
  const bf16* Vp = Vf + (size_t)bh * SEQ * DK;

  bf16x8 qf[4];
#pragma unroll
  for (int kd = 0; kd < 4; kd++)
    qf[kd] = *reinterpret_cast<const bf16x8*>(&Qp[kd * 512 + lane * 8]);

  f32x16 ot0, ot1;
#pragma unroll
  for (int r = 0; r < 16; r++) { ot0[r] = 0.f; ot1[r] = 0.f; }
  float m_run = -1e30f, l_run = 0.f;

  bf16x8 ka[2][4], kb2[2][4];

#define LOADK(dst, tt)                                                          \
  {                                                                             \
    const bf16* kbase_ = Kp + (size_t)(tt) * 4096 + lane * 8;                   \
    _Pragma("unroll") for (int hf = 0; hf < 2; hf++)                            \
        _Pragma("unroll") for (int kd = 0; kd < 4; kd++)                        \
            dst[hf][kd] = *reinterpret_cast<const bf16x8*>(                     \
                &kbase_[(hf * 4 + kd) * 512]);                                  \
  }

  // prologue: K[0], K[1] in flight; S[0] computed
  LOADK(ka, 0)
  LOADK(kb2, 1)
  f32x16 sa0, sa1, sb0, sb1;
#pragma unroll
  for (int r = 0; r < 16; r++) { sa0[r] = 0.f; sa1[r] = 0.f; }
  __builtin_amdgcn_s_setprio(1);
#pragma unroll
  for (int kd = 0; kd < 4; kd++)
    sa0 = __builtin_amdgcn_mfma_f32_32x32x16_bf16(ka[0][kd], qf[kd], sa0, 0, 0, 0);
#pragma unroll
  for (int kd = 0; kd < 4; kd++)
    sa1 = __builtin_amdgcn_mfma_f32_32x32x16_bf16(ka[1][kd], qf[kd], sa1, 0, 0, 0);
  __builtin_amdgcn_s_setprio(0);

  auto pipe = [&](f32x16& SC0, f32x16& SC1, f32x16& SN0, f32x16& SN1,
                  bf16x8 (&KN)[2][4], bf16x8 (&KL)[2][4], int tc) {
    // --- QK^T for tile tc+1 (MFMA, overlaps softmax below) ---
#pragma unroll
    for (int r = 0; r < 16; r++) { SN0[r] = 0.f; SN1[r] = 0.f; }
    __builtin_amdgcn_s_setprio(1);
#pragma unroll
    for (int kd = 0; kd < 4; kd++)
      SN0 = __builtin_amdgcn_mfma_f32_32x32x16_bf16(KN[0][kd], qf[kd], SN0, 0, 0, 0);
#pragma unroll
    for (int kd = 0; kd < 4; kd++)
      SN1 = __builtin_amdgcn_mfma_f32_32x32x16_bf16(KN[1][kd], qf[kd], SN1, 0, 0, 0);
    __builtin_amdgcn_s_setprio(0);

    // --- prefetch K[tc+2] (wrapped; unused past last tile) ---
    LOADK(KL, (tc + 2) & (NT - 1))

    // --- V fragments for tile tc (latency hidden under softmax) ---
    bf16x8 vf[2][4];
    {
      const bf16* vbase_ = Vp + (size_t)tc * 4096 + lane * 8;
#pragma unroll
      for (int dh = 0; dh < 2; dh++)
#pragma unroll
        for (int ks = 0; ks < 4; ks++)
          vf[dh][ks] = *reinterpret_cast<const bf16x8*>(&vbase_[(dh * 4 + ks) * 512]);
    }

    // --- online softmax on SC (exp2 domain), defer-rescale (T13) ---
    float w16[16];
#pragma unroll
    for (int r = 0; r < 16; r++) w16[r] = fmaxf(SC0[r], SC1[r]);
#pragma unroll
    for (int r = 0; r < 8; r++) w16[r] = fmaxf(w16[r], w16[r + 8]);
#pragma unroll
    for (int r = 0; r < 4; r++) w16[r] = fmaxf(w16[r], w16[r + 4]);
    float mx = fmaxf(fmaxf(w16[0], w16[1]), fmaxf(w16[2], w16[3]));
    mx = xhalf_max(mx);
    if (__any(mx > m_run + DEFER_THR)) {
      const float mn = fmaxf(m_run, mx);
      const float alpha = fast_exp2(m_run - mn);
      m_run = mn;
      l_run *= alpha;
#pragma unroll
      for (int r = 0; r < 16; r++) { ot0[r] *= alpha; ot1[r] *= alpha; }
    }
    float p[32];
#pragma unroll
    for (int r = 0; r < 16; r++) p[r] = fast_exp2(SC0[r] - m_run);
#pragma unroll
    for (int r = 0; r < 16; r++) p[16 + r] = fast_exp2(SC1[r] - m_run);
    float a16[16];
#pragma unroll
    for (int r = 0; r < 16; r++) a16[r] = p[r] + p[r + 16];
#pragma unroll
    for (int r = 0; r < 8; r++) a16[r] += a16[r + 8];
#pragma unroll
    for (int r = 0; r < 4; r++) a16[r] += a16[r + 4];
    float rs = (a16[0] + a16[1]) + (a16[2] + a16[3]);
    l_run += xhalf_add(rs);

    // --- pack P -> P^T B-fragments (cvt_pk + permlane32_swap) ---
    u32 c[16];
#pragma unroll
    for (int i = 0; i < 8; i++) c[i] = cvtpk_bf16(p[2 * i], p[2 * i + 1]);
#pragma unroll
    for (int i = 0; i < 8; i++) c[8 + i] = cvtpk_bf16(p[16 + 2 * i], p[17 + 2 * i]);
    plswap(c[0], c[2]);   plswap(c[1], c[3]);
    plswap(c[4], c[6]);   plswap(c[5], c[7]);
    plswap(c[8], c[10]);  plswap(c[9], c[11]);
    plswap(c[12], c[14]); plswap(c[13], c[15]);
    bf16x8 pbv[4];
#pragma unroll
    for (int ks = 0; ks < 4; ks++) {
      union { u32 u[4]; bf16x8 v; } pk;
      pk.u[0] = c[ks * 4 + 0]; pk.u[1] = c[ks * 4 + 1];
      pk.u[2] = c[ks * 4 + 2]; pk.u[3] = c[ks * 4 + 3];
      pbv[ks] = pk.v;
    }

    // --- O^T += V^T . P^T ---
    __builtin_amdgcn_s_setprio(1);
#pragma unroll
    for (int ks = 0; ks < 4; ks++) {
      ot0 = __builtin_amdgcn_mfma_f32_32x32x16_bf16(vf[0][ks], pbv[ks], ot0, 0, 0, 0);
      ot1 = __builtin_amdgcn_mfma_f32_32x32x16_bf16(vf[1][ks], pbv[ks], ot1, 0, 0, 0);
    }
    __builtin_amdgcn_s_setprio(0);
  };

  for (int t = 0; t < NT; t += 2) {
    pipe(sa0, sa1, sb0, sb1, kb2, ka, t);       // softmax tile t,   QK tile t+1
    pipe(sb0, sb1, sa0, sa1, ka, kb2, t + 1);   // softmax tile t+1, QK tile t+2
  }

  // --- epilogue: lane holds O^T[d][q=row], d = 32*dh + 8*g + 4*hi + j ---
  const float inv = 1.0f / l_run;
  bf16* Xp = X + ((size_t)bb * SEQ + q0 + row) * D_MODEL + hh * DK;
#pragma unroll
  for (int g = 0; g < 4; g++) {
    bf16x4 w0, w1;
#pragma unroll
    for (int j = 0; j < 4; j++) {
      w0[j] = (bf16)(ot0[g * 4 + j] * inv);
      w1[j] = (bf16)(ot1[g * 4 + j] * inv);
    }
    *reinterpret_cast<bf16x4*>(&Xp[g * 8 + hi * 4]) = w0;
    *reinterpret_cast<bf16x4*>(&Xp[32 + g * 8 + hi * 4]) = w1;
  }
}

// ---------------------------------------------------------------------------
extern "C" void kernel_launch(void* const* d_in, const int* in_sizes, int n_in,
                              void* d_out, int out_size, void* d_ws, size_t ws_size,
                              hipStream_t stream) {
  const float* q  = (const float*)d_in[0];
  const float* k  = (const float*)d_in[1];
  const float* v  = (const float*)d_in[2];
  const float* Wq = (const float*)d_in[3];
  const float* bq = (const float*)d_in[4];
  const float* Wk = (const float*)d_in[5];
  const float* bk = (const float*)d_in[6];
  const float* Wv = (const float*)d_in[7];
  const float* bv = (const float*)d_in[8];
  const float* Wo = (const float*)d_in[9];
  const float* bo = (const float*)d_in[10];

  char* ws = (char*)d_ws;
  size_t off = 0;
  auto alloc = [&](size_t bytes) -> void* {
    void* p = ws + off;
    off += (bytes + 255) & ~(size_t)255;
    return p;
  };
  const size_t ACT = (size_t)NTOK * D_MODEL;
  const size_t WEL = (size_t)D_MODEL * D_MODEL;

  bf16* Xq  = (bf16*)alloc(ACT * 2);
  bf16* Xk  = (bf16*)alloc(ACT * 2);
  bf16* Xv  = (bf16*)alloc(ACT * 2);
  bf16* Wqb = (bf16*)alloc(WEL * 2);
  bf16* Wkb = (bf16*)alloc(WEL * 2);
  bf16* Wvb = (bf16*)alloc(WEL * 2);
  bf16* Wob = (bf16*)alloc(WEL * 2);
  bf16* Qfb = (bf16*)alloc(ACT * 2);
  bf16* Kfb = (bf16*)alloc(ACT * 2);
  bf16* Vfb = (bf16*)alloc(ACT * 2);
  bf16* Xa  = (bf16*)alloc(ACT * 2);

  {
    int n4 = (int)(ACT / 4);
    cvt3_kernel<<<dim3((n4 + 255) / 256, 3), dim3(256), 0, stream>>>(q, k, v, Xq, Xk, Xv, n4);
  }
  {
    int n4 = (int)(WEL / 4);
    cvt4_kernel<<<dim3((n4 + 255) / 256, 4), dim3(256), 0, stream>>>(
        Wq, Wk, Wv, Wo, Wqb, Wkb, Wvb, Wob, n4);
  }

  ProjArgs pa;
  pa.A[0] = Xq;  pa.A[1] = Xk;  pa.A[2] = Xv;
  pa.W[0] = Wqb; pa.W[1] = Wkb; pa.W[2] = Wvb;
  pa.bias[0] = bq; pa.bias[1] = bk; pa.bias[2] = bv;
  pa.out[0] = Qfb; pa.out[1] = Kfb; pa.out[2] = Vfb;
  gemm_proj<<<dim3(NTOK / TM, D_MODEL / TN, 3), dim3(256), 0, stream>>>(pa, D_MODEL);

  attn_kernel<<<dim3(SEQ / (QBLK * 4), BATCH * NHEADS), dim3(256), 0, stream>>>(
      Qfb, Kfb, Vfb, Xa);

  gemm_out<<<dim3(NTOK / TM, D_MODEL / TN), dim3(256), 0, stream>>>(
      Xa, Wob, bo, (float*)d_out, D_MODEL);
}

// Round 9
// 143.442 us; speedup vs baseline: 3.3521x; 1.0391x over previous
//
#include <hip/hip_runtime.h>
#include <hip/hip_bf16.h>

typedef __bf16 bf16;
typedef __attribute__((ext_vector_type(4))) __bf16 bf16x4;
typedef __attribute__((ext_vector_type(8))) __bf16 bf16x8;
typedef __attribute__((ext_vector_type(4))) float f32x4;
typedef __attribute__((ext_vector_type(16))) float f32x16;
typedef unsigned int u32;

#define D_MODEL 1024
#define NHEADS 16
#define DK 64
#define BATCH 2
#define SEQ 2048
#define NTOK (BATCH * SEQ)   // 4096

// 1/sqrt(64) * log2(e) folded into Q projection -> softmax runs in exp2 domain
#define QSCALE 0.18033688011112042f
#define DEFER_THR 8.0f       // defer O-rescale unless max grows by >8 (2^8 bound on P)

__device__ __forceinline__ u32 cvtpk_bf16(float lo, float hi) {
  u32 r;
  asm("v_cvt_pk_bf16_f32 %0, %1, %2" : "=v"(r) : "v"(lo), "v"(hi));
  return r;
}
__device__ __forceinline__ void plswap(u32& a, u32& b) {
  asm("v_permlane32_swap_b32 %0, %1" : "+v"(a), "+v"(b));
}
__device__ __forceinline__ float fast_exp2(float x) {
#if __has_builtin(__builtin_amdgcn_exp2f)
  return __builtin_amdgcn_exp2f(x);
#else
  return exp2f(x);
#endif
}
// Cross-half (lane ^ 32) combine — __shfl_xor (proven; hand-rolled permlane
// asm was a regalloc/hazard trap, R3/R4 post-mortems).
__device__ __forceinline__ float xhalf_max(float x) {
  return fmaxf(x, __shfl_xor(x, 32));
}
__device__ __forceinline__ float xhalf_add(float x) {
  return x + __shfl_xor(x, 32);
}

// ---------------------------------------------------------------------------
// Fragment-packed layouts (per head, SEQ*DK elems each). Lane l = hi*32+row.
//   Qf: [s/32][kd 0..3][lane][8]     lane supplies B-frag col=s&31, k=kd*16+hi*8+j
//   Kf: [s/64][hf*4+kd][lane][8]     A-frag row=s&31 (hf half), k=kd*16+hi*8+j
//   Vf: [s/64][dh*4+ks][lane][8]     A-frag row d=dh*32+(d&31), kv=ks*16+hi*8+j
// Every attn load = base + lane*16B + const  ->  one coalesced 1KB transaction.
// ---------------------------------------------------------------------------
__device__ __forceinline__ int frag_off_q(int s, int d) {
  return ((s >> 5) << 11) + ((d >> 4) << 9) + ((((d >> 3) & 1) * 32 + (s & 31)) << 3) + (d & 7);
}
__device__ __forceinline__ int frag_off_k(int s, int d) {
  return ((s >> 6) << 12) + ((((s >> 5) & 1) * 4 + (d >> 4)) << 9) +
         ((((d >> 3) & 1) * 32 + (s & 31)) << 3) + (d & 7);
}
__device__ __forceinline__ int frag_off_v(int s, int d) {
  return ((s >> 6) << 12) + (((d >> 5) * 4 + ((s >> 4) & 3)) << 9) +
         ((((s >> 3) & 1) * 32 + (d & 31)) << 3) + (s & 7);
}

// ---------------------------------------------------------------------------
// fp32 -> bf16 conversions, batched launches
// ---------------------------------------------------------------------------
__global__ __launch_bounds__(256) void cvt3_kernel(
    const float* __restrict__ s0, const float* __restrict__ s1, const float* __restrict__ s2,
    bf16* __restrict__ d0, bf16* __restrict__ d1, bf16* __restrict__ d2, int n4) {
  int i = blockIdx.x * blockDim.x + threadIdx.x;
  if (i >= n4) return;
  const float* s = blockIdx.y == 0 ? s0 : blockIdx.y == 1 ? s1 : s2;
  bf16* d = blockIdx.y == 0 ? d0 : blockIdx.y == 1 ? d1 : d2;
  float4 v = reinterpret_cast<const float4*>(s)[i];
  bf16x4 o;
  o[0] = (bf16)v.x; o[1] = (bf16)v.y; o[2] = (bf16)v.z; o[3] = (bf16)v.w;
  reinterpret_cast<bf16x4*>(d)[i] = o;
}

__global__ __launch_bounds__(256) void cvt4_kernel(
    const float* __restrict__ s0, const float* __restrict__ s1,
    const float* __restrict__ s2, const float* __restrict__ s3,
    bf16* __restrict__ d0, bf16* __restrict__ d1, bf16* __restrict__ d2, bf16* __restrict__ d3,
    int n4) {
  int i = blockIdx.x * blockDim.x + threadIdx.x;
  if (i >= n4) return;
  const float* s = blockIdx.y == 0 ? s0 : blockIdx.y == 1 ? s1 : blockIdx.y == 2 ? s2 : s3;
  bf16* d = blockIdx.y == 0 ? d0 : blockIdx.y == 1 ? d1 : blockIdx.y == 2 ? d2 : d3;
  float4 v = reinterpret_cast<const float4*>(s)[i];
  bf16x4 o;
  o[0] = (bf16)v.x; o[1] = (bf16)v.y; o[2] = (bf16)v.z; o[3] = (bf16)v.w;
  reinterpret_cast<bf16x4*>(d)[i] = o;
}

#define ASYNC_COPY16(gptr, lptr)                                                \
  __builtin_amdgcn_global_load_lds(                                             \
      (__attribute__((address_space(1))) void*)(gptr),                          \
      (__attribute__((address_space(3))) void*)(lptr), 16, 0, 0)

// ---------------------------------------------------------------------------
// Projection GEMM: 128x128 tile (m97-structure: 4 waves 2x2, 4x4 frags,
// 16 MFMA per 8 ds_read_b128). grid.z selects Q/K/V; epilogue writes the
// fragment-packed layout.
// ---------------------------------------------------------------------------
struct ProjArgs {
  const bf16* A[3];
  const bf16* W[3];
  const float* bias[3];
  bf16* out[3];
};

__global__ __launch_bounds__(256) void gemm_proj(ProjArgs pa, int K) {
  __shared__ bf16 As[128][32];
  __shared__ bf16 Bs[128][32];
  const int z = blockIdx.z;
  const bf16* A = pa.A[z];
  const bf16* Bw = pa.W[z];
  const int m0 = blockIdx.x * 128;
  const int n0 = blockIdx.y * 128;

  const int t = threadIdx.x;
  const int wave = t >> 6;
  const int lane = t & 63;
  const int wr = (wave >> 1) * 64;
  const int wc = (wave & 1) * 64;
  const int r4 = lane >> 2;
  const int c8 = (lane & 3) * 8;
  const int fr = lane & 15;
  const int fk = (lane >> 4) * 8;

  f32x4 acc[4][4] = {};

  for (int k0 = 0; k0 < K; k0 += 32) {
    ASYNC_COPY16(&A[(size_t)(m0 + wave * 16 + r4) * K + k0 + c8], &As[wave * 16][0]);
    ASYNC_COPY16(&A[(size_t)(m0 + 64 + wave * 16 + r4) * K + k0 + c8], &As[64 + wave * 16][0]);
    ASYNC_COPY16(&Bw[(size_t)(n0 + wave * 16 + r4) * K + k0 + c8], &Bs[wave * 16][0]);
    ASYNC_COPY16(&Bw[(size_t)(n0 + 64 + wave * 16 + r4) * K + k0 + c8], &Bs[64 + wave * 16][0]);
    __syncthreads();

    bf16x8 af[4], bfr[4];
#pragma unroll
    for (int m = 0; m < 4; m++)
      af[m] = *reinterpret_cast<const bf16x8*>(&As[wr + m * 16 + fr][fk]);
#pragma unroll
    for (int n = 0; n < 4; n++)
      bfr[n] = *reinterpret_cast<const bf16x8*>(&Bs[wc + n * 16 + fr][fk]);
#pragma unroll
    for (int m = 0; m < 4; m++)
#pragma unroll
      for (int n = 0; n < 4; n++)
        acc[m][n] = __builtin_amdgcn_mfma_f32_16x16x32_bf16(af[m], bfr[n], acc[m][n], 0, 0, 0);
    __syncthreads();
  }

  const float scale = (z == 0) ? QSCALE : 1.0f;
  const float* bias = pa.bias[z];
  bf16* out = pa.out[z];
#pragma unroll
  for (int m = 0; m < 4; m++) {
#pragma unroll
    for (int n = 0; n < 4; n++) {
      const int col = n0 + wc + n * 16 + fr;
      const float bv = bias[col];
#pragma unroll
      for (int j = 0; j < 4; j++) {
        const int row = m0 + wr + m * 16 + (lane >> 4) * 4 + j;
        const float v = (acc[m][n][j] + bv) * scale;
        const int b = row >> 11;
        const int s = row & (SEQ - 1);
        const int h = col >> 6;
        const int d = col & (DK - 1);
        const size_t base = (size_t)(b * NHEADS + h) * SEQ * DK;
        int off;
        if (z == 0)      off = frag_off_q(s, d);
        else if (z == 1) off = frag_off_k(s, d);
        else             off = frag_off_v(s, d);
        out[base + off] = (bf16)v;
      }
    }
  }
}

// ---------------------------------------------------------------------------
// Output GEMM: 128x64 tile (unchanged from R8).
// ---------------------------------------------------------------------------
#define TM 128
#define TN 64
#define BK 32

__global__ __launch_bounds__(256) void gemm_out(
    const bf16* __restrict__ A, const bf16* __restrict__ Bw,
    const float* __restrict__ bias, float* __restrict__ out, int K) {
  __shared__ bf16 As[TM][BK];
  __shared__ bf16 Bs[TN][BK];
  const int m0 = blockIdx.x * TM;
  const int n0 = blockIdx.y * TN;

  const int t = threadIdx.x;
  const int wave = t >> 6;
  const int lane = t & 63;
  const int wr = (wave >> 1) * 64;
  const int wc = (wave & 1) * 32;
  const int r4 = lane >> 2;
  const int c8 = (lane & 3) * 8;
  const int fr = lane & 15;
  const int fk = (lane >> 4) * 8;

  f32x4 acc[4][2] = {};
  for (int k0 = 0; k0 < K; k0 += BK) {
    ASYNC_COPY16(&A[(size_t)(m0 + wave * 16 + r4) * K + k0 + c8], &As[wave * 16][0]);
    ASYNC_COPY16(&A[(size_t)(m0 + 64 + wave * 16 + r4) * K + k0 + c8], &As[64 + wave * 16][0]);
    ASYNC_COPY16(&Bw[(size_t)(n0 + wave * 16 + r4) * K + k0 + c8], &Bs[wave * 16][0]);
    __syncthreads();

    bf16x8 af[4], bfr[2];
#pragma unroll
    for (int m = 0; m < 4; m++)
      af[m] = *reinterpret_cast<const bf16x8*>(&As[wr + m * 16 + fr][fk]);
#pragma unroll
    for (int n = 0; n < 2; n++)
      bfr[n] = *reinterpret_cast<const bf16x8*>(&Bs[wc + n * 16 + fr][fk]);
#pragma unroll
    for (int m = 0; m < 4; m++)
#pragma unroll
      for (int n = 0; n < 2; n++)
        acc[m][n] = __builtin_amdgcn_mfma_f32_16x16x32_bf16(af[m], bfr[n], acc[m][n], 0, 0, 0);
    __syncthreads();
  }

#pragma unroll
  for (int m = 0; m < 4; m++) {
#pragma unroll
    for (int n = 0; n < 2; n++) {
      const int col = n0 + wc + n * 16 + fr;
      const float bv = bias[col];
#pragma unroll
      for (int j = 0; j < 4; j++) {
        const int row = m0 + wr + m * 16 + (lane >> 4) * 4 + j;
        out[(size_t)row * D_MODEL + col] = acc[m][n][j] + bv;
      }
    }
  }
}

// ---------------------------------------------------------------------------
// Flash attention: swapped-operand 32x32x16, fragment-packed loads (R8),
// split-KV across 2 waves/block (R7 merge). Wave w handles tiles t≡w (mod 2);
// per-wave 2-deep QK||softmax pipeline, K prefetch distance 2 (local),
// defer-rescale, setprio. One barrier + LDS merge at the end.
// 2048 blocks x 2 waves = 4096 waves = 4/SIMD (R8 was 2/SIMD, latency-bound).
// ---------------------------------------------------------------------------
#define QBLK 32
#define KVBLK 64
#define NT (SEQ / KVBLK)   // 32
#define NLOC (NT / 2)      // 16 tiles per wave

__global__ __launch_bounds__(128, 2) void attn_kernel(
    const bf16* __restrict__ Qf,  // packed (frag_off_q), pre-scaled
    const bf16* __restrict__ Kf,  // packed (frag_off_k)
    const bf16* __restrict__ Vf,  // packed (frag_off_v)
    bf16* __restrict__ X) {       // [B][SEQ][D_MODEL]
  __shared__ float lds_o[32][64];   // wave1 partial O^T
  __shared__ float lds_ml[2][64];   // wave1 m, l

  const int lane = threadIdx.x & 63;
  const int wave = threadIdx.x >> 6;
  const int bh = blockIdx.y;
  const int bb = bh >> 4, hh = bh & (NHEADS - 1);
  const int q0 = blockIdx.x * QBLK;
  const int row = lane & 31, hi = lane >> 5;

  const bf16* Qp = Qf + (size_t)bh * SEQ * DK + (size_t)q0 * DK;
  const bf16* Kp = Kf + (size_t)bh * SEQ * DK;
  const bf16* Vp = Vf + (size_t)bh * SEQ * DK;

  bf16x8 qf[4];
#pragma unroll
  for (int kd = 0; kd < 4; kd++)
    qf[kd] = *reinterpret_cast<const bf16x8*>(&Qp[kd * 512 + lane * 8]);

  f32x16 ot0, ot1;
#pragma unroll
  for (int r = 0; r < 16; r++) { ot0[r] = 0.f; ot1[r] = 0.f; }
  float m_run = -1e30f, l_run = 0.f;

  bf16x8 ka[2][4], kb2[2][4];

#define LOADK(dst, tt)                                                          \
  {                                                                             \
    const bf16* kbase_ = Kp + (size_t)(tt) * 4096 + lane * 8;                   \
    _Pragma("unroll") for (int hf = 0; hf < 2; hf++)                            \
        _Pragma("unroll") for (int kd = 0; kd < 4; kd++)                        \
            dst[hf][kd] = *reinterpret_cast<const bf16x8*>(                     \
                &kbase_[(hf * 4 + kd) * 512]);                                  \
  }

  // local tile i (0..15) -> global tile index (wave-interleaved), wrapped
  auto gt = [&](int i) { return wave + 2 * (i & (NLOC - 1)); };

  // prologue: K for local tiles 0,1 in flight; S[local 0] computed
  LOADK(ka, gt(0))
  LOADK(kb2, gt(1))
  f32x16 sa0, sa1, sb0, sb1;
#pragma unroll
  for (int r = 0; r < 16; r++) { sa0[r] = 0.f; sa1[r] = 0.f; }
  __builtin_amdgcn_s_setprio(1);
#pragma unroll
  for (int kd = 0; kd < 4; kd++)
    sa0 = __builtin_amdgcn_mfma_f32_32x32x16_bf16(ka[0][kd], qf[kd], sa0, 0, 0, 0);
#pragma unroll
  for (int kd = 0; kd < 4; kd++)
    sa1 = __builtin_amdgcn_mfma_f32_32x32x16_bf16(ka[1][kd], qf[kd], sa1, 0, 0, 0);
  __builtin_amdgcn_s_setprio(0);

  auto pipe = [&](f32x16& SC0, f32x16& SC1, f32x16& SN0, f32x16& SN1,
                  bf16x8 (&KN)[2][4], bf16x8 (&KL)[2][4], int tc, int tp) {
    // --- QK^T for next local tile (MFMA, overlaps softmax below) ---
#pragma unroll
    for (int r = 0; r < 16; r++) { SN0[r] = 0.f; SN1[r] = 0.f; }
    __builtin_amdgcn_s_setprio(1);
#pragma unroll
    for (int kd = 0; kd < 4; kd++)
      SN0 = __builtin_amdgcn_mfma_f32_32x32x16_bf16(KN[0][kd], qf[kd], SN0, 0, 0, 0);
#pragma unroll
    for (int kd = 0; kd < 4; kd++)
      SN1 = __builtin_amdgcn_mfma_f32_32x32x16_bf16(KN[1][kd], qf[kd], SN1, 0, 0, 0);
    __builtin_amdgcn_s_setprio(0);

    // --- prefetch K[tp] (wrapped; value unused past last tile) ---
    LOADK(KL, tp)

    // --- V fragments for tile tc (latency hidden under softmax) ---
    bf16x8 vf[2][4];
    {
      const bf16* vbase_ = Vp + (size_t)tc * 4096 + lane * 8;
#pragma unroll
      for (int dh = 0; dh < 2; dh++)
#pragma unroll
        for (int ks = 0; ks < 4; ks++)
          vf[dh][ks] = *reinterpret_cast<const bf16x8*>(&vbase_[(dh * 4 + ks) * 512]);
    }

    // --- online softmax on SC (exp2 domain), defer-rescale (T13) ---
    float w16[16];
#pragma unroll
    for (int r = 0; r < 16; r++) w16[r] = fmaxf(SC0[r], SC1[r]);
#pragma unroll
    for (int r = 0; r < 8; r++) w16[r] = fmaxf(w16[r], w16[r + 8]);
#pragma unroll
    for (int r = 0; r < 4; r++) w16[r] = fmaxf(w16[r], w16[r + 4]);
    float mx = fmaxf(fmaxf(w16[0], w16[1]), fmaxf(w16[2], w16[3]));
    mx = xhalf_max(mx);
    if (__any(mx > m_run + DEFER_THR)) {
      const float mn = fmaxf(m_run, mx);
      const float alpha = fast_exp2(m_run - mn);
      m_run = mn;
      l_run *= alpha;
#pragma unroll
      for (int r = 0; r < 16; r++) { ot0[r] *= alpha; ot1[r] *= alpha; }
    }
    float p[32];
#pragma unroll
    for (int r = 0; r < 16; r++) p[r] = fast_exp2(SC0[r] - m_run);
#pragma unroll
    for (int r = 0; r < 16; r++) p[16 + r] = fast_exp2(SC1[r] - m_run);
    float a16[16];
#pragma unroll
    for (int r = 0; r < 16; r++) a16[r] = p[r] + p[r + 16];
#pragma unroll
    for (int r = 0; r < 8; r++) a16[r] += a16[r + 8];
#pragma unroll
    for (int r = 0; r < 4; r++) a16[r] += a16[r + 4];
    float rs = (a16[0] + a16[1]) + (a16[2] + a16[3]);
    l_run += xhalf_add(rs);

    // --- pack P -> P^T B-fragments (cvt_pk + permlane32_swap) ---
    u32 c[16];
#pragma unroll
    for (int i = 0; i < 8; i++) c[i] = cvtpk_bf16(p[2 * i], p[2 * i + 1]);
#pragma unroll
    for (int i = 0; i < 8; i++) c[8 + i] = cvtpk_bf16(p[16 + 2 * i], p[17 + 2 * i]);
    plswap(c[0], c[2]);   plswap(c[1], c[3]);
    plswap(c[4], c[6]);   plswap(c[5], c[7]);
    plswap(c[8], c[10]);  plswap(c[9], c[11]);
    plswap(c[12], c[14]); plswap(c[13], c[15]);
    bf16x8 pbv[4];
#pragma unroll
    for (int ks = 0; ks < 4; ks++) {
      union { u32 u[4]; bf16x8 v; } pk;
      pk.u[0] = c[ks * 4 + 0]; pk.u[1] = c[ks * 4 + 1];
      pk.u[2] = c[ks * 4 + 2]; pk.u[3] = c[ks * 4 + 3];
      pbv[ks] = pk.v;
    }

    // --- O^T += V^T . P^T ---
    __builtin_amdgcn_s_setprio(1);
#pragma unroll
    for (int ks = 0; ks < 4; ks++) {
      ot0 = __builtin_amdgcn_mfma_f32_32x32x16_bf16(vf[0][ks], pbv[ks], ot0, 0, 0, 0);
      ot1 = __builtin_amdgcn_mfma_f32_32x32x16_bf16(vf[1][ks], pbv[ks], ot1, 0, 0, 0);
    }
    __builtin_amdgcn_s_setprio(0);
  };

  for (int i = 0; i < NLOC; i += 2) {
    pipe(sa0, sa1, sb0, sb1, kb2, ka, gt(i), gt(i + 2));
    pipe(sb0, sb1, sa0, sa1, ka, kb2, gt(i + 1), gt(i + 3));
  }

  // ---- merge the two waves' partials (wave1 -> LDS, wave0 combines) ----
  if (wave == 1) {
#pragma unroll
    for (int r = 0; r < 16; r++) {
      lds_o[r][lane] = ot0[r];
      lds_o[16 + r][lane] = ot1[r];
    }
    lds_ml[0][lane] = m_run;
    lds_ml[1][lane] = l_run;
  }
  __syncthreads();
  if (wave == 0) {
    const float m1 = lds_ml[0][lane];
    const float l1 = lds_ml[1][lane];
    const float mm = fmaxf(m_run, m1);
    const float s0 = fast_exp2(m_run - mm);
    const float s1 = fast_exp2(m1 - mm);
    const float inv = 1.0f / (l_run * s0 + l1 * s1);
    bf16* Xp = X + ((size_t)bb * SEQ + q0 + row) * D_MODEL + hh * DK;
#pragma unroll
    for (int g = 0; g < 4; g++) {
      bf16x4 w0, w1;
#pragma unroll
      for (int j = 0; j < 4; j++) {
        w0[j] = (bf16)((ot0[g * 4 + j] * s0 + lds_o[g * 4 + j][lane] * s1) * inv);
        w1[j] = (bf16)((ot1[g * 4 + j] * s0 + lds_o[16 + g * 4 + j][lane] * s1) * inv);
      }
      *reinterpret_cast<bf16x4*>(&Xp[g * 8 + hi * 4]) = w0;
      *reinterpret_cast<bf16x4*>(&Xp[32 + g * 8 + hi * 4]) = w1;
    }
  }
}

// ---------------------------------------------------------------------------
extern "C" void kernel_launch(void* const* d_in, const int* in_sizes, int n_in,
                              void* d_out, int out_size, void* d_ws, size_t ws_size,
                              hipStream_t stream) {
  const float* q  = (const float*)d_in[0];
  const float* k  = (const float*)d_in[1];
  const float* v  = (const float*)d_in[2];
  const float* Wq = (const float*)d_in[3];
  const float* bq = (const float*)d_in[4];
  const float* Wk = (const float*)d_in[5];
  const float* bk = (const float*)d_in[6];
  const float* Wv = (const float*)d_in[7];
  const float* bv = (const float*)d_in[8];
  const float* Wo = (const float*)d_in[9];
  const float* bo = (const float*)d_in[10];

  char* ws = (char*)d_ws;
  size_t off = 0;
  auto alloc = [&](size_t bytes) -> void* {
    void* p = ws + off;
    off += (bytes + 255) & ~(size_t)255;
    return p;
  };
  const size_t ACT = (size_t)NTOK * D_MODEL;
  const size_t WEL = (size_t)D_MODEL * D_MODEL;

  bf16* Xq  = (bf16*)alloc(ACT * 2);
  bf16* Xk  = (bf16*)alloc(ACT * 2);
  bf16* Xv  = (bf16*)alloc(ACT * 2);
  bf16* Wqb = (bf16*)alloc(WEL * 2);
  bf16* Wkb = (bf16*)alloc(WEL * 2);
  bf16* Wvb = (bf16*)alloc(WEL * 2);
  bf16* Wob = (bf16*)alloc(WEL * 2);
  bf16* Qfb = (bf16*)alloc(ACT * 2);
  bf16* Kfb = (bf16*)alloc(ACT * 2);
  bf16* Vfb = (bf16*)alloc(ACT * 2);
  bf16* Xa  = (bf16*)alloc(ACT * 2);

  {
    int n4 = (int)(ACT / 4);
    cvt3_kernel<<<dim3((n4 + 255) / 256, 3), dim3(256), 0, stream>>>(q, k, v, Xq, Xk, Xv, n4);
  }
  {
    int n4 = (int)(WEL / 4);
    cvt4_kernel<<<dim3((n4 + 255) / 256, 4), dim3(256), 0, stream>>>(
        Wq, Wk, Wv, Wo, Wqb, Wkb, Wvb, Wob, n4);
  }

  ProjArgs pa;
  pa.A[0] = Xq;  pa.A[1] = Xk;  pa.A[2] = Xv;
  pa.W[0] = Wqb; pa.W[1] = Wkb; pa.W[2] = Wvb;
  pa.bias[0] = bq; pa.bias[1] = bk; pa.bias[2] = bv;
  pa.out[0] = Qfb; pa.out[1] = Kfb; pa.out[2] = Vfb;
  gemm_proj<<<dim3(NTOK / 128, D_MODEL / 128, 3), dim3(256), 0, stream>>>(pa, D_MODEL);

  attn_kernel<<<dim3(SEQ / QBLK, BATCH * NHEADS), dim3(128), 0, stream>>>(
      Qfb, Kfb, Vfb, Xa);

  gemm_out<<<dim3(NTOK / TM, D_MODEL / TN), dim3(256), 0, stream>>>(
      Xa, Wob, bo, (float*)d_out, D_MODEL);
}

// Round 10
// 136.892 us; speedup vs baseline: 3.5125x; 1.0479x over previous
//
#include <hip/hip_runtime.h>
#include <hip/hip_bf16.h>

typedef __bf16 bf16;
typedef __attribute__((ext_vector_type(4))) __bf16 bf16x4;
typedef __attribute__((ext_vector_type(8))) __bf16 bf16x8;
typedef __attribute__((ext_vector_type(4))) float f32x4;
typedef __attribute__((ext_vector_type(16))) float f32x16;
typedef unsigned int u32;

#define D_MODEL 1024
#define NHEADS 16
#define DK 64
#define BATCH 2
#define SEQ 2048
#define NTOK (BATCH * SEQ)   // 4096

// 1/sqrt(64) * log2(e) folded into Q projection -> softmax runs in exp2 domain
#define QSCALE 0.18033688011112042f
#define DEFER_THR 8.0f       // defer O-rescale unless max grows by >8 (2^8 bound on P)

__device__ __forceinline__ u32 cvtpk_bf16(float lo, float hi) {
  u32 r;
  asm("v_cvt_pk_bf16_f32 %0, %1, %2" : "=v"(r) : "v"(lo), "v"(hi));
  return r;
}
__device__ __forceinline__ void plswap(u32& a, u32& b) {
  asm("v_permlane32_swap_b32 %0, %1" : "+v"(a), "+v"(b));
}
__device__ __forceinline__ float fast_exp2(float x) {
#if __has_builtin(__builtin_amdgcn_exp2f)
  return __builtin_amdgcn_exp2f(x);
#else
  return exp2f(x);
#endif
}
// Cross-half (lane ^ 32) combine — __shfl_xor (proven; hand-rolled permlane
// asm was a regalloc/hazard trap, R3/R4 post-mortems).
__device__ __forceinline__ float xhalf_max(float x) {
  return fmaxf(x, __shfl_xor(x, 32));
}
__device__ __forceinline__ float xhalf_add(float x) {
  return x + __shfl_xor(x, 32);
}

// ---------------------------------------------------------------------------
// Fragment-packed layouts (per head, SEQ*DK elems each). Lane l = hi*32+row.
//   Qf: [s/32][kd 0..3][lane][8]     lane supplies B-frag col=s&31, k=kd*16+hi*8+j
//   Kf: [s/64][hf*4+kd][lane][8]     A-frag row=s&31 (hf half), k=kd*16+hi*8+j
//   Vf: [s/64][dh*4+ks][lane][8]     A-frag row d=dh*32+(d&31), kv=ks*16+hi*8+j
// Every attn load = base + lane*16B + const  ->  one coalesced 1KB transaction.
// ---------------------------------------------------------------------------
__device__ __forceinline__ int frag_off_q(int s, int d) {
  return ((s >> 5) << 11) + ((d >> 4) << 9) + ((((d >> 3) & 1) * 32 + (s & 31)) << 3) + (d & 7);
}
__device__ __forceinline__ int frag_off_k(int s, int d) {
  return ((s >> 6) << 12) + ((((s >> 5) & 1) * 4 + (d >> 4)) << 9) +
         ((((d >> 3) & 1) * 32 + (s & 31)) << 3) + (d & 7);
}
__device__ __forceinline__ int frag_off_v(int s, int d) {
  return ((s >> 6) << 12) + (((d >> 5) * 4 + ((s >> 4) & 3)) << 9) +
         ((((s >> 3) & 1) * 32 + (d & 31)) << 3) + (s & 7);
}

// ---------------------------------------------------------------------------
// fp32 -> bf16 conversions, batched launches
// ---------------------------------------------------------------------------
__global__ __launch_bounds__(256) void cvt3_kernel(
    const float* __restrict__ s0, const float* __restrict__ s1, const float* __restrict__ s2,
    bf16* __restrict__ d0, bf16* __restrict__ d1, bf16* __restrict__ d2, int n4) {
  int i = blockIdx.x * blockDim.x + threadIdx.x;
  if (i >= n4) return;
  const float* s = blockIdx.y == 0 ? s0 : blockIdx.y == 1 ? s1 : s2;
  bf16* d = blockIdx.y == 0 ? d0 : blockIdx.y == 1 ? d1 : d2;
  float4 v = reinterpret_cast<const float4*>(s)[i];
  bf16x4 o;
  o[0] = (bf16)v.x; o[1] = (bf16)v.y; o[2] = (bf16)v.z; o[3] = (bf16)v.w;
  reinterpret_cast<bf16x4*>(d)[i] = o;
}

__global__ __launch_bounds__(256) void cvt4_kernel(
    const float* __restrict__ s0, const float* __restrict__ s1,
    const float* __restrict__ s2, const float* __restrict__ s3,
    bf16* __restrict__ d0, bf16* __restrict__ d1, bf16* __restrict__ d2, bf16* __restrict__ d3,
    int n4) {
  int i = blockIdx.x * blockDim.x + threadIdx.x;
  if (i >= n4) return;
  const float* s = blockIdx.y == 0 ? s0 : blockIdx.y == 1 ? s1 : blockIdx.y == 2 ? s2 : s3;
  bf16* d = blockIdx.y == 0 ? d0 : blockIdx.y == 1 ? d1 : blockIdx.y == 2 ? d2 : d3;
  float4 v = reinterpret_cast<const float4*>(s)[i];
  bf16x4 o;
  o[0] = (bf16)v.x; o[1] = (bf16)v.y; o[2] = (bf16)v.z; o[3] = (bf16)v.w;
  reinterpret_cast<bf16x4*>(d)[i] = o;
}

#define ASYNC_COPY16(gptr, lptr)                                                \
  __builtin_amdgcn_global_load_lds(                                             \
      (__attribute__((address_space(1))) void*)(gptr),                          \
      (__attribute__((address_space(3))) void*)(lptr), 16, 0, 0)

// ---------------------------------------------------------------------------
// Projection GEMM: 128x128 tile; grid.z selects Q/K/V; epilogue writes the
// fragment-packed layout.
// ---------------------------------------------------------------------------
struct ProjArgs {
  const bf16* A[3];
  const bf16* W[3];
  const float* bias[3];
  bf16* out[3];
};

__global__ __launch_bounds__(256) void gemm_proj(ProjArgs pa, int K) {
  __shared__ bf16 As[128][32];
  __shared__ bf16 Bs[128][32];
  const int z = blockIdx.z;
  const bf16* A = pa.A[z];
  const bf16* Bw = pa.W[z];
  const int m0 = blockIdx.x * 128;
  const int n0 = blockIdx.y * 128;

  const int t = threadIdx.x;
  const int wave = t >> 6;
  const int lane = t & 63;
  const int wr = (wave >> 1) * 64;
  const int wc = (wave & 1) * 64;
  const int r4 = lane >> 2;
  const int c8 = (lane & 3) * 8;
  const int fr = lane & 15;
  const int fk = (lane >> 4) * 8;

  f32x4 acc[4][4] = {};

  for (int k0 = 0; k0 < K; k0 += 32) {
    ASYNC_COPY16(&A[(size_t)(m0 + wave * 16 + r4) * K + k0 + c8], &As[wave * 16][0]);
    ASYNC_COPY16(&A[(size_t)(m0 + 64 + wave * 16 + r4) * K + k0 + c8], &As[64 + wave * 16][0]);
    ASYNC_COPY16(&Bw[(size_t)(n0 + wave * 16 + r4) * K + k0 + c8], &Bs[wave * 16][0]);
    ASYNC_COPY16(&Bw[(size_t)(n0 + 64 + wave * 16 + r4) * K + k0 + c8], &Bs[64 + wave * 16][0]);
    __syncthreads();

    bf16x8 af[4], bfr[4];
#pragma unroll
    for (int m = 0; m < 4; m++)
      af[m] = *reinterpret_cast<const bf16x8*>(&As[wr + m * 16 + fr][fk]);
#pragma unroll
    for (int n = 0; n < 4; n++)
      bfr[n] = *reinterpret_cast<const bf16x8*>(&Bs[wc + n * 16 + fr][fk]);
#pragma unroll
    for (int m = 0; m < 4; m++)
#pragma unroll
      for (int n = 0; n < 4; n++)
        acc[m][n] = __builtin_amdgcn_mfma_f32_16x16x32_bf16(af[m], bfr[n], acc[m][n], 0, 0, 0);
    __syncthreads();
  }

  const float scale = (z == 0) ? QSCALE : 1.0f;
  const float* bias = pa.bias[z];
  bf16* out = pa.out[z];
#pragma unroll
  for (int m = 0; m < 4; m++) {
#pragma unroll
    for (int n = 0; n < 4; n++) {
      const int col = n0 + wc + n * 16 + fr;
      const float bv = bias[col];
#pragma unroll
      for (int j = 0; j < 4; j++) {
        const int row = m0 + wr + m * 16 + (lane >> 4) * 4 + j;
        const float v = (acc[m][n][j] + bv) * scale;
        const int b = row >> 11;
        const int s = row & (SEQ - 1);
        const int h = col >> 6;
        const int d = col & (DK - 1);
        const size_t base = (size_t)(b * NHEADS + h) * SEQ * DK;
        int off;
        if (z == 0)      off = frag_off_q(s, d);
        else if (z == 1) off = frag_off_k(s, d);
        else             off = frag_off_v(s, d);
        out[base + off] = (bf16)v;
      }
    }
  }
}

// ---------------------------------------------------------------------------
// Output GEMM: 128x64 tile (unchanged).
// ---------------------------------------------------------------------------
#define TM 128
#define TN 64
#define BK 32

__global__ __launch_bounds__(256) void gemm_out(
    const bf16* __restrict__ A, const bf16* __restrict__ Bw,
    const float* __restrict__ bias, float* __restrict__ out, int K) {
  __shared__ bf16 As[TM][BK];
  __shared__ bf16 Bs[TN][BK];
  const int m0 = blockIdx.x * TM;
  const int n0 = blockIdx.y * TN;

  const int t = threadIdx.x;
  const int wave = t >> 6;
  const int lane = t & 63;
  const int wr = (wave >> 1) * 64;
  const int wc = (wave & 1) * 32;
  const int r4 = lane >> 2;
  const int c8 = (lane & 3) * 8;
  const int fr = lane & 15;
  const int fk = (lane >> 4) * 8;

  f32x4 acc[4][2] = {};
  for (int k0 = 0; k0 < K; k0 += BK) {
    ASYNC_COPY16(&A[(size_t)(m0 + wave * 16 + r4) * K + k0 + c8], &As[wave * 16][0]);
    ASYNC_COPY16(&A[(size_t)(m0 + 64 + wave * 16 + r4) * K + k0 + c8], &As[64 + wave * 16][0]);
    ASYNC_COPY16(&Bw[(size_t)(n0 + wave * 16 + r4) * K + k0 + c8], &Bs[wave * 16][0]);
    __syncthreads();

    bf16x8 af[4], bfr[2];
#pragma unroll
    for (int m = 0; m < 4; m++)
      af[m] = *reinterpret_cast<const bf16x8*>(&As[wr + m * 16 + fr][fk]);
#pragma unroll
    for (int n = 0; n < 2; n++)
      bfr[n] = *reinterpret_cast<const bf16x8*>(&Bs[wc + n * 16 + fr][fk]);
#pragma unroll
    for (int m = 0; m < 4; m++)
#pragma unroll
      for (int n = 0; n < 2; n++)
        acc[m][n] = __builtin_amdgcn_mfma_f32_16x16x32_bf16(af[m], bfr[n], acc[m][n], 0, 0, 0);
    __syncthreads();
  }

#pragma unroll
  for (int m = 0; m < 4; m++) {
#pragma unroll
    for (int n = 0; n < 2; n++) {
      const int col = n0 + wc + n * 16 + fr;
      const float bv = bias[col];
#pragma unroll
      for (int j = 0; j < 4; j++) {
        const int row = m0 + wr + m * 16 + (lane >> 4) * 4 + j;
        out[(size_t)row * D_MODEL + col] = acc[m][n][j] + bv;
      }
    }
  }
}

// ---------------------------------------------------------------------------
// Flash attention: R8 structure (4 waves/block, each wave 32 q-rows over all
// KV tiles, fragment-packed loads, 2-deep QK||softmax pipeline, defer-rescale,
// setprio) + XCD-locality swizzle: 1D grid of 512 blocks, block i -> XCD i&7;
// each XCD gets 4 heads only -> per-XCD K/V working set 2 MB, fits 4 MB L2.
// Without this, all 32 heads (32 MB) thrash every L2 and all K/V traffic
// (~1 GB/dispatch) is served by L3 at its BW ceiling (R8/R9 plateau).
// ---------------------------------------------------------------------------
#define QBLK 32
#define KVBLK 64
#define NT (SEQ / KVBLK)   // 32

__global__ __launch_bounds__(256, 2) void attn_kernel(
    const bf16* __restrict__ Qf,  // packed (frag_off_q), pre-scaled
    const bf16* __restrict__ Kf,  // packed (frag_off_k)
    const bf16* __restrict__ Vf,  // packed (frag_off_v)
    bf16* __restrict__ X) {       // [B][SEQ][D_MODEL]
  const int lane = threadIdx.x & 63;
  const int wave = threadIdx.x >> 6;

  // --- XCD-locality swizzle (512 blocks, XCD = linear id & 7 round-robin) ---
  const int i = blockIdx.x;
  const int xcd = i & 7;
  const int slot = i >> 3;         // 0..63
  const int hgrp = slot >> 4;      // 0..3
  const int xq = slot & 15;        // 0..15 q-block within head
  const int bh = xcd + 8 * hgrp;   // 4 heads per XCD
  const int bb = bh >> 4, hh = bh & (NHEADS - 1);
  const int q0 = xq * (QBLK * 4) + wave * QBLK;
  const int row = lane & 31, hi = lane >> 5;

  const bf16* Qp = Qf + (size_t)bh * SEQ * DK + (size_t)q0 * DK;
  const bf16* Kp = Kf + (size_t)bh * SEQ * DK;
  const bf16* Vp = Vf + (size_t)bh * SEQ * DK;

  bf16x8 qf[4];
#pragma unroll
  for (int kd = 0; kd < 4; kd++)
    qf[kd] = *reinterpret_cast<const bf16x8*>(&Qp[kd * 512 + lane * 8]);

  f32x16 ot0, ot1;
#pragma unroll
  for (int r = 0; r < 16; r++) { ot0[r] = 0.f; ot1[r] = 0.f; }
  float m_run = -1e30f, l_run = 0.f;

  bf16x8 ka[2][4], kb2[2][4];

#define LOADK(dst, tt)                                                          \
  {                                                                             \
    const bf16* kbase_ = Kp + (size_t)(tt) * 4096 + lane * 8;                   \
    _Pragma("unroll") for (int hf = 0; hf < 2; hf++)                            \
        _Pragma("unroll") for (int kd = 0; kd < 4; kd++)                        \
            dst[hf][kd] = *reinterpret_cast<const bf16x8*>(                     \
                &kbase_[(hf * 4 + kd) * 512]);                                  \
  }

  // prologue: K[0], K[1] in flight; S[0] computed
  LOADK(ka, 0)
  LOADK(kb2, 1)
  f32x16 sa0, sa1, sb0, sb1;
#pragma unroll
  for (int r = 0; r < 16; r++) { sa0[r] = 0.f; sa1[r] = 0.f; }
  __builtin_amdgcn_s_setprio(1);
#pragma unroll
  for (int kd = 0; kd < 4; kd++)
    sa0 = __builtin_amdgcn_mfma_f32_32x32x16_bf16(ka[0][kd], qf[kd], sa0, 0, 0, 0);
#pragma unroll
  for (int kd = 0; kd < 4; kd++)
    sa1 = __builtin_amdgcn_mfma_f32_32x32x16_bf16(ka[1][kd], qf[kd], sa1, 0, 0, 0);
  __builtin_amdgcn_s_setprio(0);

  auto pipe = [&](f32x16& SC0, f32x16& SC1, f32x16& SN0, f32x16& SN1,
                  bf16x8 (&KN)[2][4], bf16x8 (&KL)[2][4], int tc) {
    // --- QK^T for tile tc+1 (MFMA, overlaps softmax below) ---
#pragma unroll
    for (int r = 0; r < 16; r++) { SN0[r] = 0.f; SN1[r] = 0.f; }
    __builtin_amdgcn_s_setprio(1);
#pragma unroll
    for (int kd = 0; kd < 4; kd++)
      SN0 = __builtin_amdgcn_mfma_f32_32x32x16_bf16(KN[0][kd], qf[kd], SN0, 0, 0, 0);
#pragma unroll
    for (int kd = 0; kd < 4; kd++)
      SN1 = __builtin_amdgcn_mfma_f32_32x32x16_bf16(KN[1][kd], qf[kd], SN1, 0, 0, 0);
    __builtin_amdgcn_s_setprio(0);

    // --- prefetch K[tc+2] (wrapped; unused past last tile) ---
    LOADK(KL, (tc + 2) & (NT - 1))

    // --- V fragments for tile tc (latency hidden under softmax) ---
    bf16x8 vf[2][4];
    {
      const bf16* vbase_ = Vp + (size_t)tc * 4096 + lane * 8;
#pragma unroll
      for (int dh = 0; dh < 2; dh++)
#pragma unroll
        for (int ks = 0; ks < 4; ks++)
          vf[dh][ks] = *reinterpret_cast<const bf16x8*>(&vbase_[(dh * 4 + ks) * 512]);
    }

    // --- online softmax on SC (exp2 domain), defer-rescale (T13) ---
    float w16[16];
#pragma unroll
    for (int r = 0; r < 16; r++) w16[r] = fmaxf(SC0[r], SC1[r]);
#pragma unroll
    for (int r = 0; r < 8; r++) w16[r] = fmaxf(w16[r], w16[r + 8]);
#pragma unroll
    for (int r = 0; r < 4; r++) w16[r] = fmaxf(w16[r], w16[r + 4]);
    float mx = fmaxf(fmaxf(w16[0], w16[1]), fmaxf(w16[2], w16[3]));
    mx = xhalf_max(mx);
    if (__any(mx > m_run + DEFER_THR)) {
      const float mn = fmaxf(m_run, mx);
      const float alpha = fast_exp2(m_run - mn);
      m_run = mn;
      l_run *= alpha;
#pragma unroll
      for (int r = 0; r < 16; r++) { ot0[r] *= alpha; ot1[r] *= alpha; }
    }
    float p[32];
#pragma unroll
    for (int r = 0; r < 16; r++) p[r] = fast_exp2(SC0[r] - m_run);
#pragma unroll
    for (int r = 0; r < 16; r++) p[16 + r] = fast_exp2(SC1[r] - m_run);
    float a16[16];
#pragma unroll
    for (int r = 0; r < 16; r++) a16[r] = p[r] + p[r + 16];
#pragma unroll
    for (int r = 0; r < 8; r++) a16[r] += a16[r + 8];
#pragma unroll
    for (int r = 0; r < 4; r++) a16[r] += a16[r + 4];
    float rs = (a16[0] + a16[1]) + (a16[2] + a16[3]);
    l_run += xhalf_add(rs);

    // --- pack P -> P^T B-fragments (cvt_pk + permlane32_swap) ---
    u32 c[16];
#pragma unroll
    for (int i2 = 0; i2 < 8; i2++) c[i2] = cvtpk_bf16(p[2 * i2], p[2 * i2 + 1]);
#pragma unroll
    for (int i2 = 0; i2 < 8; i2++) c[8 + i2] = cvtpk_bf16(p[16 + 2 * i2], p[17 + 2 * i2]);
    plswap(c[0], c[2]);   plswap(c[1], c[3]);
    plswap(c[4], c[6]);   plswap(c[5], c[7]);
    plswap(c[8], c[10]);  plswap(c[9], c[11]);
    plswap(c[12], c[14]); plswap(c[13], c[15]);
    bf16x8 pbv[4];
#pragma unroll
    for (int ks = 0; ks < 4; ks++) {
      union { u32 u[4]; bf16x8 v; } pk;
      pk.u[0] = c[ks * 4 + 0]; pk.u[1] = c[ks * 4 + 1];
      pk.u[2] = c[ks * 4 + 2]; pk.u[3] = c[ks * 4 + 3];
      pbv[ks] = pk.v;
    }

    // --- O^T += V^T . P^T ---
    __builtin_amdgcn_s_setprio(1);
#pragma unroll
    for (int ks = 0; ks < 4; ks++) {
      ot0 = __builtin_amdgcn_mfma_f32_32x32x16_bf16(vf[0][ks], pbv[ks], ot0, 0, 0, 0);
      ot1 = __builtin_amdgcn_mfma_f32_32x32x16_bf16(vf[1][ks], pbv[ks], ot1, 0, 0, 0);
    }
    __builtin_amdgcn_s_setprio(0);
  };

  for (int t = 0; t < NT; t += 2) {
    pipe(sa0, sa1, sb0, sb1, kb2, ka, t);       // softmax tile t,   QK tile t+1
    pipe(sb0, sb1, sa0, sa1, ka, kb2, t + 1);   // softmax tile t+1, QK tile t+2
  }

  // --- epilogue: lane holds O^T[d][q=row], d = 32*dh + 8*g + 4*hi + j ---
  const float inv = 1.0f / l_run;
  bf16* Xp = X + ((size_t)bb * SEQ + q0 + row) * D_MODEL + hh * DK;
#pragma unroll
  for (int g = 0; g < 4; g++) {
    bf16x4 w0, w1;
#pragma unroll
    for (int j = 0; j < 4; j++) {
      w0[j] = (bf16)(ot0[g * 4 + j] * inv);
      w1[j] = (bf16)(ot1[g * 4 + j] * inv);
    }
    *reinterpret_cast<bf16x4*>(&Xp[g * 8 + hi * 4]) = w0;
    *reinterpret_cast<bf16x4*>(&Xp[32 + g * 8 + hi * 4]) = w1;
  }
}

// ---------------------------------------------------------------------------
extern "C" void kernel_launch(void* const* d_in, const int* in_sizes, int n_in,
                              void* d_out, int out_size, void* d_ws, size_t ws_size,
                              hipStream_t stream) {
  const float* q  = (const float*)d_in[0];
  const float* k  = (const float*)d_in[1];
  const float* v  = (const float*)d_in[2];
  const float* Wq = (const float*)d_in[3];
  const float* bq = (const float*)d_in[4];
  const float* Wk = (const float*)d_in[5];
  const float* bk = (const float*)d_in[6];
  const float* Wv = (const float*)d_in[7];
  const float* bv = (const float*)d_in[8];
  const float* Wo = (const float*)d_in[9];
  const float* bo = (const float*)d_in[10];

  char* ws = (char*)d_ws;
  size_t off = 0;
  auto alloc = [&](size_t bytes) -> void* {
    void* p = ws + off;
    off += (bytes + 255) & ~(size_t)255;
    return p;
  };
  const size_t ACT = (size_t)NTOK * D_MODEL;
  const size_t WEL = (size_t)D_MODEL * D_MODEL;

  bf16* Xq  = (bf16*)alloc(ACT * 2);
  bf16* Xk  = (bf16*)alloc(ACT * 2);
  bf16* Xv  = (bf16*)alloc(ACT * 2);
  bf16* Wqb = (bf16*)alloc(WEL * 2);
  bf16* Wkb = (bf16*)alloc(WEL * 2);
  bf16* Wvb = (bf16*)alloc(WEL * 2);
  bf16* Wob = (bf16*)alloc(WEL * 2);
  bf16* Qfb = (bf16*)alloc(ACT * 2);
  bf16* Kfb = (bf16*)alloc(ACT * 2);
  bf16* Vfb = (bf16*)alloc(ACT * 2);
  bf16* Xa  = (bf16*)alloc(ACT * 2);

  {
    int n4 = (int)(ACT / 4);
    cvt3_kernel<<<dim3((n4 + 255) / 256, 3), dim3(256), 0, stream>>>(q, k, v, Xq, Xk, Xv, n4);
  }
  {
    int n4 = (int)(WEL / 4);
    cvt4_kernel<<<dim3((n4 + 255) / 256, 4), dim3(256), 0, stream>>>(
        Wq, Wk, Wv, Wo, Wqb, Wkb, Wvb, Wob, n4);
  }

  ProjArgs pa;
  pa.A[0] = Xq;  pa.A[1] = Xk;  pa.A[2] = Xv;
  pa.W[0] = Wqb; pa.W[1] = Wkb; pa.W[2] = Wvb;
  pa.bias[0] = bq; pa.bias[1] = bk; pa.bias[2] = bv;
  pa.out[0] = Qfb; pa.out[1] = Kfb; pa.out[2] = Vfb;
  gemm_proj<<<dim3(NTOK / 128, D_MODEL / 128, 3), dim3(256), 0, stream>>>(pa, D_MODEL);

  attn_kernel<<<dim3(512), dim3(256), 0, stream>>>(Qfb, Kfb, Vfb, Xa);

  gemm_out<<<dim3(NTOK / TM, D_MODEL / TN), dim3(256), 0, stream>>>(
      Xa, Wob, bo, (float*)d_out, D_MODEL);
}